// Round 4
// baseline (404.367 us; speedup 1.0000x reference)
//
#include <hip/hip_runtime.h>
#include <cstdint>
#include <cstddef>

typedef __attribute__((ext_vector_type(8))) short short8;
typedef __attribute__((ext_vector_type(4))) float f32x4;

#define D_MODEL 1024
#define NHEADS 16
#define DHEAD 64
#define BATCH 4
#define SEQ 2048
#define MTOK (BATCH * SEQ)

__device__ __forceinline__ unsigned short f2bf(float f) {
  union { float f; unsigned u; } v; v.f = f;
  unsigned r = v.u + 0x7fffu + ((v.u >> 16) & 1u);
  return (unsigned short)(r >> 16);
}
__device__ __forceinline__ float bf2f(unsigned short u) {
  union { unsigned u; float f; } v; v.u = ((unsigned)u) << 16;
  return v.f;
}
__device__ __forceinline__ unsigned cvt_pk_bf16(float a, float b) {
  unsigned u;
  asm("v_cvt_pk_bf16_f32 %0, %1, %2" : "=v"(u) : "v"(a), "v"(b));
  return u;
}

typedef const __attribute__((address_space(1))) unsigned int* gas1_t;
typedef __attribute__((address_space(3))) unsigned int* las3_t;
// async global->LDS, 16B per lane; LDS dest must be wave-uniform base (HW adds lane*16B)
__device__ __forceinline__ void gload16(const unsigned short* g, unsigned short* l) {
  __builtin_amdgcn_global_load_lds((gas1_t)g, (las3_t)l, 16, 0, 0);
}

#define MFMA_BF16(a, b, c) __builtin_amdgcn_mfma_f32_16x16x32_bf16(a, b, c, 0, 0, 0)

// ---------------- fp32 -> bf16 conversion (weights) ----------------
__global__ __launch_bounds__(256) void f32_to_bf16(const float* __restrict__ src,
                                                   unsigned short* __restrict__ dst, int n4) {
  int i = blockIdx.x * 256 + threadIdx.x;
  if (i >= n4) return;
  float4 v = ((const float4*)src)[i];
  ushort4 o;
  o.x = f2bf(v.x); o.y = f2bf(v.y); o.z = f2bf(v.z); o.w = f2bf(v.w);
  ((ushort4*)dst)[i] = o;
}

// ---------------- LayerNorm: fp32 in -> bf16 out ----------------
__global__ __launch_bounds__(256) void ln_fwd(const float* __restrict__ x, const float* __restrict__ g,
                                              const float* __restrict__ b,
                                              unsigned short* __restrict__ out) {
  const int row = blockIdx.x, t = threadIdx.x;
  float4 v = *(const float4*)(x + (size_t)row * D_MODEL + t * 4);
  float s = v.x + v.y + v.z + v.w;
  float s2 = v.x * v.x + v.y * v.y + v.z * v.z + v.w * v.w;
#pragma unroll
  for (int m = 1; m < 64; m <<= 1) { s += __shfl_xor(s, m); s2 += __shfl_xor(s2, m); }
  __shared__ float red[8];
  int wv = t >> 6;
  if ((t & 63) == 0) { red[wv] = s; red[4 + wv] = s2; }
  __syncthreads();
  s = red[0] + red[1] + red[2] + red[3];
  s2 = red[4] + red[5] + red[6] + red[7];
  float mu = s * (1.f / D_MODEL);
  float var = s2 * (1.f / D_MODEL) - mu * mu;
  float rs = rsqrtf(var + 1e-5f);
  float4 gg = *(const float4*)(g + t * 4);
  float4 bb = *(const float4*)(b + t * 4);
  ushort4 o;
  o.x = f2bf((v.x - mu) * rs * gg.x + bb.x);
  o.y = f2bf((v.y - mu) * rs * gg.y + bb.y);
  o.z = f2bf((v.z - mu) * rs * gg.z + bb.z);
  o.w = f2bf((v.w - mu) * rs * gg.w + bb.w);
  *(ushort4*)(out + (size_t)row * D_MODEL + t * 4) = o;
}

// ---------------- GEMM v2 (m97 structure): C[M,N] = A[M,K] * B[N,K]^T ----------------
// global_load_lds width=16 into linear [128][32] double-buffered LDS; 1 barrier/K-step.
// Linear layout is conflict-free for the fragment ds_read_b128 (row stride 64B:
// 8 lanes per 4-bank window). EPI: 0 bf16, 1 fp32 R+acc, 2 bf16 relu(acc).
template <int EPI>
__global__ __launch_bounds__(256) void gemm_bt2(const unsigned short* __restrict__ A,
                                                const unsigned short* __restrict__ B,
                                                const float* __restrict__ R,
                                                void* __restrict__ Cout, int M, int N, int K) {
  constexpr int BM = 128, BN = 128, BK = 32;
  __shared__ unsigned short lA[2][BM * BK], lB[2][BN * BK];
  const int tid = threadIdx.x, lane = tid & 63, wave = tid >> 6;
  const int lo = lane & 15, g = lane >> 4;
  const int bm = blockIdx.y * BM, bn = blockIdx.x * BN;
  const int wr = wave >> 1, wc = wave & 1;
  f32x4 acc[4][4] = {};
  // staging chunks: 512 x 16B per tile; wave w covers chunks [w*128, w*128+128)
  // chunk c -> LDS shorts [c*8, c*8+8) ; global row c>>2, col (c&3)*8
  const int c0 = wave * 128 + lane, c1 = c0 + 64;
  const unsigned short* gA0 = A + (size_t)(bm + (c0 >> 2)) * K + (c0 & 3) * 8;
  const unsigned short* gA1 = A + (size_t)(bm + (c1 >> 2)) * K + (c1 & 3) * 8;
  const unsigned short* gB0 = B + (size_t)(bn + (c0 >> 2)) * K + (c0 & 3) * 8;
  const unsigned short* gB1 = B + (size_t)(bn + (c1 >> 2)) * K + (c1 & 3) * 8;
  const int nk = K / BK;
  auto stage = [&](int buf, int kt) {
    const size_t ko = (size_t)kt * BK;
    gload16(gA0 + ko, &lA[buf][(wave * 128) * 8]);
    gload16(gA1 + ko, &lA[buf][(wave * 128 + 64) * 8]);
    gload16(gB0 + ko, &lB[buf][(wave * 128) * 8]);
    gload16(gB1 + ko, &lB[buf][(wave * 128 + 64) * 8]);
  };
  stage(0, 0);
  for (int kt = 0; kt < nk; ++kt) {
    __syncthreads();  // drains vmcnt: buf[kt&1] complete; prior reads of buf[(kt+1)&1] done
    if (kt + 1 < nk) stage((kt + 1) & 1, kt + 1);  // flies under the MFMAs below
    const unsigned short* La = &lA[kt & 1][0];
    const unsigned short* Lb = &lB[kt & 1][0];
    short8 af[4], bfr[4];
#pragma unroll
    for (int m = 0; m < 4; ++m)
      af[m] = *(const short8*)(La + (wr * 64 + m * 16 + lo) * BK + g * 8);
#pragma unroll
    for (int n = 0; n < 4; ++n)
      bfr[n] = *(const short8*)(Lb + (wc * 64 + n * 16 + lo) * BK + g * 8);
#pragma unroll
    for (int m = 0; m < 4; ++m)
#pragma unroll
      for (int n = 0; n < 4; ++n) acc[m][n] = MFMA_BF16(af[m], bfr[n], acc[m][n]);
  }
  const int r0 = bm + wr * 64 + g * 4;
  const int c0c = bn + wc * 64 + lo;
#pragma unroll
  for (int m = 0; m < 4; ++m)
#pragma unroll
    for (int n = 0; n < 4; ++n) {
#pragma unroll
      for (int r = 0; r < 4; ++r) {
        size_t off = (size_t)(r0 + m * 16 + r) * N + (c0c + n * 16);
        float v = acc[m][n][r];
        if (EPI == 0) ((unsigned short*)Cout)[off] = f2bf(v);
        else if (EPI == 1) ((float*)Cout)[off] = R[off] + v;
        else ((unsigned short*)Cout)[off] = f2bf(fmaxf(v, 0.f));
      }
    }
}

// ---------------- prep: l2-normalize q (x invT), k in place; transpose v -> Vt[b,h,d,n] ----------------
__global__ __launch_bounds__(256) void prep_qkv(unsigned short* __restrict__ qkv,
                                                unsigned short* __restrict__ vt,
                                                const float* __restrict__ temp) {
  __shared__ unsigned short tile[64][80];
  const int blk = blockIdx.x;
  const int ntile = blk & 31, h = (blk >> 5) & 15, b = blk >> 9;
  const int t = threadIdx.x;
  const float invT = 1.0f / temp[0];
  const int tt = t >> 2, c4 = t & 3;  // token-in-tile, 16-elem chunk
  size_t rowbase = (size_t)(b * SEQ + ntile * 64 + tt) * 3072 + h * 64 + c4 * 16;
#pragma unroll
  for (int pk = 0; pk < 2; ++pk) {  // q then k
    unsigned short* p = qkv + rowbase + pk * 1024;
    short8 v0 = *(const short8*)p;
    short8 v1 = *(const short8*)(p + 8);
    float f[16];
#pragma unroll
    for (int j = 0; j < 8; ++j) {
      f[j] = bf2f((unsigned short)v0[j]);
      f[8 + j] = bf2f((unsigned short)v1[j]);
    }
    float ss = 0.f;
#pragma unroll
    for (int j = 0; j < 16; ++j) ss += f[j] * f[j];
    ss += __shfl_xor(ss, 1);
    ss += __shfl_xor(ss, 2);
    float sc = 1.0f / fmaxf(sqrtf(ss), 1e-12f);
    if (pk == 0) sc *= invT;  // fold 1/temperature into q
    short8 o0, o1;
#pragma unroll
    for (int j = 0; j < 8; ++j) {
      o0[j] = (short)f2bf(f[j] * sc);
      o1[j] = (short)f2bf(f[8 + j] * sc);
    }
    *(short8*)p = o0;
    *(short8*)(p + 8) = o1;
  }
  const unsigned short* pv = qkv + rowbase + 2048;
  *(short8*)&tile[tt][c4 * 16] = *(const short8*)pv;
  *(short8*)&tile[tt][c4 * 16 + 8] = *(const short8*)(pv + 8);
  __syncthreads();
  const int d = tt;
  short8 o0, o1;
#pragma unroll
  for (int j = 0; j < 8; ++j) o0[j] = (short)tile[c4 * 16 + j][d];
#pragma unroll
  for (int j = 0; j < 8; ++j) o1[j] = (short)tile[c4 * 16 + 8 + j][d];
  size_t vr = (size_t)((b * NHEADS + h) * DHEAD + d) * SEQ + ntile * 64 + c4 * 16;
  *(short8*)(vt + vr) = o0;
  *(short8*)(vt + vr + 8) = o1;
}

// ---------------- flash attention v4: swapped QK^T + defer-max (T13) + setprio (T5) ----------------
__global__ __launch_bounds__(512) void attn_fwd4(const unsigned short* __restrict__ qkv,
                                                 const unsigned short* __restrict__ vt,
                                                 unsigned short* __restrict__ out) {
  constexpr int LDT = 72;  // K/V LDS row stride (shorts)
  constexpr int LDP = 66;  // P strip row stride (shorts)
  __shared__ unsigned short lK[2][64 * LDT];
  __shared__ unsigned short lV[2][64 * LDT];
  __shared__ unsigned short pP[8][16 * LDP];
  const int blk = blockIdx.x;
  const int qt = blk & 15, h = (blk >> 4) & 15, b = blk >> 8;
  const int tid = threadIdx.x, lane = tid & 63, wave = tid >> 6;
  const int lo = lane & 15, g = lane >> 4;
  const int qr0 = qt * 128 + wave * 16;
  // Q fragments (B-operand): lane holds Q[q=lo][d = g*8.. , +32]
  const unsigned short* qrow = qkv + (size_t)(b * SEQ + qr0 + lo) * 3072 + h * 64 + g * 8;
  const short8 qf0 = *(const short8*)qrow;
  const short8 qf1 = *(const short8*)(qrow + 32);
  // cooperative staging: 512 threads x 16B = one 64x64 bf16 tile per array
  const int srow = tid >> 3, scol = (tid & 7) * 8;
  const unsigned short* gK = qkv + (size_t)(b * SEQ + srow) * 3072 + 1024 + h * 64 + scol;
  const unsigned short* gV = vt + ((size_t)((b * NHEADS + h) * DHEAD) + srow) * SEQ + scol;
  short8 rk = *(const short8*)gK;
  short8 rv = *(const short8*)gV;
  *(short8*)&lK[0][srow * LDT + scol] = rk;
  *(short8*)&lV[0][srow * LDT + scol] = rv;
  f32x4 o[4] = {};
  float mrow = -1e30f, lrow = 0.f;
  const f32x4 fzero = {};
  unsigned short* Pb = &pP[wave][0];
  constexpr int NT = SEQ / 64;
  for (int t = 0; t < NT; ++t) {
    __syncthreads();  // staged writes for tile t visible; all waves done with tile t-1
    const unsigned short* Kb = &lK[t & 1][0];
    const unsigned short* Vb = &lV[t & 1][0];
    if (t + 1 < NT) {  // issue next-tile global loads now; consumed at loop bottom
      rk = *(const short8*)(gK + (size_t)(t + 1) * 64 * 3072);
      rv = *(const short8*)(gV + (t + 1) * 64);
    }
    // QK^T (swapped): s[jt][r] = S[k = jt*16 + g*4 + r][q = lo]   (invT pre-folded into Q)
    f32x4 s[4];
    __builtin_amdgcn_s_setprio(1);
#pragma unroll
    for (int jt = 0; jt < 4; ++jt) {
      short8 kf0 = *(const short8*)(Kb + (jt * 16 + lo) * LDT + g * 8);
      short8 kf1 = *(const short8*)(Kb + (jt * 16 + lo) * LDT + 32 + g * 8);
      s[jt] = MFMA_BF16(kf1, qf1, MFMA_BF16(kf0, qf0, fzero));
    }
    __builtin_amdgcn_s_setprio(0);
    // tile max: 16 in-reg + cross-g (xor 16/32)
    float t0 = fmaxf(fmaxf(s[0][0], s[0][1]), fmaxf(s[0][2], s[0][3]));
    float t1 = fmaxf(fmaxf(s[1][0], s[1][1]), fmaxf(s[1][2], s[1][3]));
    float t2 = fmaxf(fmaxf(s[2][0], s[2][1]), fmaxf(s[2][2], s[2][3]));
    float t3 = fmaxf(fmaxf(s[3][0], s[3][1]), fmaxf(s[3][2], s[3][3]));
    float mx = fmaxf(fmaxf(t0, t1), fmaxf(t2, t3));
    mx = fmaxf(mx, __shfl_xor(mx, 16));
    mx = fmaxf(mx, __shfl_xor(mx, 32));
    // T13 defer-max: only rescale when the tile max grew past m+8; P then bounded by e^8.
    if (!__all(mx <= mrow + 8.f)) {
      const float mn = fmaxf(mrow, mx);
      const float alpha = __expf(mrow - mn);
      mrow = mn;
      lrow *= alpha;
#pragma unroll
      for (int c = 0; c < 4; ++c)
#pragma unroll
        for (int r = 0; r < 4; ++r) o[c][r] *= alpha;
    }
    float ps0 = 0.f, ps1 = 0.f;
#pragma unroll
    for (int jt = 0; jt < 4; ++jt) {
      float p0 = __expf(s[jt][0] - mrow), p1 = __expf(s[jt][1] - mrow);
      float p2 = __expf(s[jt][2] - mrow), p3 = __expf(s[jt][3] - mrow);
      s[jt][0] = p0; s[jt][1] = p1; s[jt][2] = p2; s[jt][3] = p3;
      ps0 += p0 + p1;
      ps1 += p2 + p3;
    }
    lrow += ps0 + ps1;
    // P -> packed bf16 pairs -> wave-private strip (row = q = lo), b32 writes
#pragma unroll
    for (int jt = 0; jt < 4; ++jt) {
      unsigned u0 = cvt_pk_bf16(s[jt][0], s[jt][1]);
      unsigned u1 = cvt_pk_bf16(s[jt][2], s[jt][3]);
      *(unsigned*)(Pb + lo * LDP + jt * 16 + g * 4) = u0;
      *(unsigned*)(Pb + lo * LDP + jt * 16 + g * 4 + 2) = u1;
    }
    // P fragment (B-operand): lane holds P[q=lo][k = g*8.. , +32]
    short8 pb0 = *(const short8*)(Pb + lo * LDP + g * 8);
    short8 pb1 = *(const short8*)(Pb + lo * LDP + 32 + g * 8);
    // PV (swapped): o[c][r] = O[q=lo][d = c*16 + g*4 + r]
    __builtin_amdgcn_s_setprio(1);
#pragma unroll
    for (int c = 0; c < 4; ++c) {
      short8 vb0 = *(const short8*)(Vb + (c * 16 + lo) * LDT + g * 8);
      short8 vb1 = *(const short8*)(Vb + (c * 16 + lo) * LDT + 32 + g * 8);
      o[c] = MFMA_BF16(vb1, pb1, MFMA_BF16(vb0, pb0, o[c]));
    }
    __builtin_amdgcn_s_setprio(0);
    if (t + 1 < NT) {  // write prefetched tile into the other buffer
      *(short8*)&lK[(t + 1) & 1][srow * LDT + scol] = rk;
      *(short8*)&lV[(t + 1) & 1][srow * LDT + scol] = rv;
    }
  }
  // cross-g sum reduce (deferred), then normalize + packed stores
  lrow += __shfl_xor(lrow, 16);
  lrow += __shfl_xor(lrow, 32);
  const float rinv = 1.0f / lrow;
  unsigned short* orow = out + (size_t)(b * SEQ + qr0 + lo) * D_MODEL + h * 64 + g * 4;
#pragma unroll
  for (int c = 0; c < 4; ++c)
#pragma unroll
    for (int r = 0; r < 4; r += 2) {
      unsigned u = cvt_pk_bf16(o[c][r] * rinv, o[c][r + 1] * rinv);
      *(unsigned*)(orow + c * 16 + r) = u;
    }
}

// ---------------- host launch ----------------
extern "C" void kernel_launch(void* const* d_in, const int* in_sizes, int n_in, void* d_out,
                              int out_size, void* d_ws, size_t ws_size, hipStream_t stream) {
  const float* x = (const float*)d_in[0];
  const float* w_qkv = (const float*)d_in[1];
  const float* w_out = (const float*)d_in[2];
  const float* w_ffn1 = (const float*)d_in[3];
  const float* w_ffn2 = (const float*)d_in[4];
  const float* g1 = (const float*)d_in[5];
  const float* b1 = (const float*)d_in[6];
  const float* g2 = (const float*)d_in[7];
  const float* b2 = (const float*)d_in[8];
  const float* temp = (const float*)d_in[9];
  float* outp = (float*)d_out;

  char* ws = (char*)d_ws;
  size_t off = 0;
  auto alloc = [&](size_t bytes) {
    void* p = ws + off;
    off += (bytes + 255) & ~(size_t)255;
    return p;
  };
  unsigned short* wqkv_bf = (unsigned short*)alloc((size_t)3072 * 1024 * 2);
  unsigned short* wout_bf = (unsigned short*)alloc((size_t)1024 * 1024 * 2);
  unsigned short* wf1_bf = (unsigned short*)alloc((size_t)2048 * 1024 * 2);
  unsigned short* wf2_bf = (unsigned short*)alloc((size_t)1024 * 2048 * 2);
  unsigned short* h_bf = (unsigned short*)alloc((size_t)MTOK * 1024 * 2);   // reused for h2
  unsigned short* qkv_bf = (unsigned short*)alloc((size_t)MTOK * 3072 * 2); // reused for ffn1 out
  unsigned short* vt_bf = (unsigned short*)alloc((size_t)BATCH * NHEADS * DHEAD * SEQ * 2);
  unsigned short* ao_bf = (unsigned short*)alloc((size_t)MTOK * 1024 * 2);
  float* x2 = (float*)alloc((size_t)MTOK * 1024 * 4);

  // weight conversions
  f32_to_bf16<<<(3072 * 1024 / 4 + 255) / 256, 256, 0, stream>>>(w_qkv, wqkv_bf, 3072 * 1024 / 4);
  f32_to_bf16<<<(1024 * 1024 / 4 + 255) / 256, 256, 0, stream>>>(w_out, wout_bf, 1024 * 1024 / 4);
  f32_to_bf16<<<(2048 * 1024 / 4 + 255) / 256, 256, 0, stream>>>(w_ffn1, wf1_bf, 2048 * 1024 / 4);
  f32_to_bf16<<<(1024 * 2048 / 4 + 255) / 256, 256, 0, stream>>>(w_ffn2, wf2_bf, 1024 * 2048 / 4);

  // LN1
  ln_fwd<<<MTOK, 256, 0, stream>>>(x, g1, b1, h_bf);
  // qkv = h @ w_qkv^T
  gemm_bt2<0><<<dim3(3072 / 128, MTOK / 128), 256, 0, stream>>>(h_bf, wqkv_bf, nullptr,
                                                                (void*)qkv_bf, MTOK, 3072, 1024);
  // l2norm q (x 1/temp), k; build Vt
  prep_qkv<<<BATCH * NHEADS * (SEQ / 64), 256, 0, stream>>>(qkv_bf, vt_bf, temp);
  // attention
  attn_fwd4<<<BATCH * NHEADS * (SEQ / 128), 512, 0, stream>>>(qkv_bf, vt_bf, ao_bf);
  // x2 = x + attn_out @ w_out^T
  gemm_bt2<1><<<dim3(1024 / 128, MTOK / 128), 256, 0, stream>>>(ao_bf, wout_bf, x, (void*)x2, MTOK,
                                                                1024, 1024);
  // LN2
  ln_fwd<<<MTOK, 256, 0, stream>>>(x2, g2, b2, h_bf);
  // ffn1 = relu(h2 @ w_ffn1^T)  (reuse qkv buffer)
  gemm_bt2<2><<<dim3(2048 / 128, MTOK / 128), 256, 0, stream>>>(h_bf, wf1_bf, nullptr,
                                                                (void*)qkv_bf, MTOK, 2048, 1024);
  // out = x2 + ffn1 @ w_ffn2^T
  gemm_bt2<1><<<dim3(1024 / 128, MTOK / 128), 256, 0, stream>>>(qkv_bf, wf2_bf, x2, (void*)outp,
                                                                MTOK, 1024, 2048);
}

// Round 5
// 391.663 us; speedup vs baseline: 1.0324x; 1.0324x over previous
//
#include <hip/hip_runtime.h>
#include <cstdint>
#include <cstddef>
#include <math.h>

typedef __attribute__((ext_vector_type(8))) short short8;
typedef __attribute__((ext_vector_type(4))) float f32x4;

#define D_MODEL 1024
#define NHEADS 16
#define DHEAD 64
#define BATCH 4
#define SEQ 2048
#define MTOK (BATCH * SEQ)

__device__ __forceinline__ unsigned short f2bf(float f) {
  union { float f; unsigned u; } v; v.f = f;
  unsigned r = v.u + 0x7fffu + ((v.u >> 16) & 1u);
  return (unsigned short)(r >> 16);
}
__device__ __forceinline__ float bf2f(unsigned short u) {
  union { unsigned u; float f; } v; v.u = ((unsigned)u) << 16;
  return v.f;
}
__device__ __forceinline__ unsigned cvt_pk_bf16(float a, float b) {
  unsigned u;
  asm("v_cvt_pk_bf16_f32 %0, %1, %2" : "=v"(u) : "v"(a), "v"(b));
  return u;
}

typedef const __attribute__((address_space(1))) unsigned int* gas1_t;
typedef __attribute__((address_space(3))) unsigned int* las3_t;
// async global->LDS, 16B per lane; LDS dest must be wave-uniform base (HW adds lane*16B)
__device__ __forceinline__ void gload16(const unsigned short* g, unsigned short* l) {
  __builtin_amdgcn_global_load_lds((gas1_t)g, (las3_t)l, 16, 0, 0);
}

#define MFMA_BF16(a, b, c) __builtin_amdgcn_mfma_f32_16x16x32_bf16(a, b, c, 0, 0, 0)

// ---------------- fp32 -> bf16 conversion, all 4 weights in one launch ----------------
__global__ __launch_bounds__(256) void f32_to_bf16_all(const float* __restrict__ s0,
                                                       const float* __restrict__ s1,
                                                       const float* __restrict__ s2,
                                                       const float* __restrict__ s3,
                                                       unsigned short* __restrict__ d0,
                                                       unsigned short* __restrict__ d1,
                                                       unsigned short* __restrict__ d2,
                                                       unsigned short* __restrict__ d3) {
  int j = blockIdx.x * 256 + threadIdx.x;  // float4 index over concatenated ranges
  const float* s;
  unsigned short* d;
  if (j < 786432) { s = s0; d = d0; }
  else if ((j -= 786432) < 262144) { s = s1; d = d1; }
  else if ((j -= 262144) < 524288) { s = s2; d = d2; }
  else { j -= 524288; s = s3; d = d3; }
  float4 v = ((const float4*)s)[j];
  ushort4 o;
  o.x = f2bf(v.x); o.y = f2bf(v.y); o.z = f2bf(v.z); o.w = f2bf(v.w);
  ((ushort4*)d)[j] = o;
}

// ---------------- LayerNorm: fp32 in -> bf16 out ----------------
__global__ __launch_bounds__(256) void ln_fwd(const float* __restrict__ x, const float* __restrict__ g,
                                              const float* __restrict__ b,
                                              unsigned short* __restrict__ out) {
  const int row = blockIdx.x, t = threadIdx.x;
  float4 v = *(const float4*)(x + (size_t)row * D_MODEL + t * 4);
  float s = v.x + v.y + v.z + v.w;
  float s2 = v.x * v.x + v.y * v.y + v.z * v.z + v.w * v.w;
#pragma unroll
  for (int m = 1; m < 64; m <<= 1) { s += __shfl_xor(s, m); s2 += __shfl_xor(s2, m); }
  __shared__ float red[8];
  int wv = t >> 6;
  if ((t & 63) == 0) { red[wv] = s; red[4 + wv] = s2; }
  __syncthreads();
  s = red[0] + red[1] + red[2] + red[3];
  s2 = red[4] + red[5] + red[6] + red[7];
  float mu = s * (1.f / D_MODEL);
  float var = s2 * (1.f / D_MODEL) - mu * mu;
  float rs = rsqrtf(var + 1e-5f);
  float4 gg = *(const float4*)(g + t * 4);
  float4 bb = *(const float4*)(b + t * 4);
  ushort4 o;
  o.x = f2bf((v.x - mu) * rs * gg.x + bb.x);
  o.y = f2bf((v.y - mu) * rs * gg.y + bb.y);
  o.z = f2bf((v.z - mu) * rs * gg.z + bb.z);
  o.w = f2bf((v.w - mu) * rs * gg.w + bb.w);
  *(ushort4*)(out + (size_t)row * D_MODEL + t * 4) = o;
}

// ---------------- GEMM (m97 structure): C[M,N] = A[M,K] * B[N,K]^T ----------------
template <int EPI>
__global__ __launch_bounds__(256) void gemm_bt2(const unsigned short* __restrict__ A,
                                                const unsigned short* __restrict__ B,
                                                const float* __restrict__ R,
                                                void* __restrict__ Cout, int M, int N, int K) {
  constexpr int BM = 128, BN = 128, BK = 32;
  __shared__ unsigned short lA[2][BM * BK], lB[2][BN * BK];
  const int tid = threadIdx.x, lane = tid & 63, wave = tid >> 6;
  const int lo = lane & 15, g = lane >> 4;
  const int bm = blockIdx.y * BM, bn = blockIdx.x * BN;
  const int wr = wave >> 1, wc = wave & 1;
  f32x4 acc[4][4] = {};
  const int c0 = wave * 128 + lane, c1 = c0 + 64;
  const unsigned short* gA0 = A + (size_t)(bm + (c0 >> 2)) * K + (c0 & 3) * 8;
  const unsigned short* gA1 = A + (size_t)(bm + (c1 >> 2)) * K + (c1 & 3) * 8;
  const unsigned short* gB0 = B + (size_t)(bn + (c0 >> 2)) * K + (c0 & 3) * 8;
  const unsigned short* gB1 = B + (size_t)(bn + (c1 >> 2)) * K + (c1 & 3) * 8;
  const int nk = K / BK;
  auto stage = [&](int buf, int kt) {
    const size_t ko = (size_t)kt * BK;
    gload16(gA0 + ko, &lA[buf][(wave * 128) * 8]);
    gload16(gA1 + ko, &lA[buf][(wave * 128 + 64) * 8]);
    gload16(gB0 + ko, &lB[buf][(wave * 128) * 8]);
    gload16(gB1 + ko, &lB[buf][(wave * 128 + 64) * 8]);
  };
  stage(0, 0);
  for (int kt = 0; kt < nk; ++kt) {
    __syncthreads();
    if (kt + 1 < nk) stage((kt + 1) & 1, kt + 1);
    const unsigned short* La = &lA[kt & 1][0];
    const unsigned short* Lb = &lB[kt & 1][0];
    short8 af[4], bfr[4];
#pragma unroll
    for (int m = 0; m < 4; ++m)
      af[m] = *(const short8*)(La + (wr * 64 + m * 16 + lo) * BK + g * 8);
#pragma unroll
    for (int n = 0; n < 4; ++n)
      bfr[n] = *(const short8*)(Lb + (wc * 64 + n * 16 + lo) * BK + g * 8);
#pragma unroll
    for (int m = 0; m < 4; ++m)
#pragma unroll
      for (int n = 0; n < 4; ++n) acc[m][n] = MFMA_BF16(af[m], bfr[n], acc[m][n]);
  }
  const int r0 = bm + wr * 64 + g * 4;
  const int c0c = bn + wc * 64 + lo;
#pragma unroll
  for (int m = 0; m < 4; ++m)
#pragma unroll
    for (int n = 0; n < 4; ++n) {
#pragma unroll
      for (int r = 0; r < 4; ++r) {
        size_t off = (size_t)(r0 + m * 16 + r) * N + (c0c + n * 16);
        float v = acc[m][n][r];
        if (EPI == 0) ((unsigned short*)Cout)[off] = f2bf(v);
        else if (EPI == 1) ((float*)Cout)[off] = R[off] + v;
        else ((unsigned short*)Cout)[off] = f2bf(fmaxf(v, 0.f));
      }
    }
}

// ---------------- prep: l2-normalize q (x invT x log2e), k in place; v -> Vt[b,h,d,n] ----------------
__global__ __launch_bounds__(256) void prep_qkv(unsigned short* __restrict__ qkv,
                                                unsigned short* __restrict__ vt,
                                                const float* __restrict__ temp) {
  __shared__ unsigned short tile[64][80];
  const int blk = blockIdx.x;
  const int ntile = blk & 31, h = (blk >> 5) & 15, b = blk >> 9;
  const int t = threadIdx.x;
  const float qscale = 1.44269504088896f / temp[0];  // log2(e)/T folded into q
  const int tt = t >> 2, c4 = t & 3;
  size_t rowbase = (size_t)(b * SEQ + ntile * 64 + tt) * 3072 + h * 64 + c4 * 16;
#pragma unroll
  for (int pk = 0; pk < 2; ++pk) {  // q then k
    unsigned short* p = qkv + rowbase + pk * 1024;
    short8 v0 = *(const short8*)p;
    short8 v1 = *(const short8*)(p + 8);
    float f[16];
#pragma unroll
    for (int j = 0; j < 8; ++j) {
      f[j] = bf2f((unsigned short)v0[j]);
      f[8 + j] = bf2f((unsigned short)v1[j]);
    }
    float ss = 0.f;
#pragma unroll
    for (int j = 0; j < 16; ++j) ss += f[j] * f[j];
    ss += __shfl_xor(ss, 1);
    ss += __shfl_xor(ss, 2);
    float sc = 1.0f / fmaxf(sqrtf(ss), 1e-12f);
    if (pk == 0) sc *= qscale;
    short8 o0, o1;
#pragma unroll
    for (int j = 0; j < 8; ++j) {
      o0[j] = (short)f2bf(f[j] * sc);
      o1[j] = (short)f2bf(f[8 + j] * sc);
    }
    *(short8*)p = o0;
    *(short8*)(p + 8) = o1;
  }
  const unsigned short* pv = qkv + rowbase + 2048;
  *(short8*)&tile[tt][c4 * 16] = *(const short8*)pv;
  *(short8*)&tile[tt][c4 * 16 + 8] = *(const short8*)(pv + 8);
  __syncthreads();
  const int d = tt;
  short8 o0, o1;
#pragma unroll
  for (int j = 0; j < 8; ++j) o0[j] = (short)tile[c4 * 16 + j][d];
#pragma unroll
  for (int j = 0; j < 8; ++j) o1[j] = (short)tile[c4 * 16 + 8 + j][d];
  size_t vr = (size_t)((b * NHEADS + h) * DHEAD + d) * SEQ + ntile * 64 + c4 * 16;
  *(short8*)(vt + vr) = o0;
  *(short8*)(vt + vr + 8) = o1;
}

// ---------------- flash attention v5: 32 q-rows/wave (K/V reads amortized 2x) ----------------
// Swapped-operand MFMA throughout; scores arrive in log2 units (exp2 softmax).
__global__ __launch_bounds__(512) void attn_fwd5(const unsigned short* __restrict__ qkv,
                                                 const unsigned short* __restrict__ vt,
                                                 unsigned short* __restrict__ out) {
  constexpr int LDT = 72;  // K/V LDS row stride (shorts)
  constexpr int LDP = 66;  // P strip row stride (shorts)
  __shared__ unsigned short lK[2][64 * LDT];
  __shared__ unsigned short lV[2][64 * LDT];
  __shared__ unsigned short pP[16][16 * LDP];  // 2 strips per wave
  const int blk = blockIdx.x;
  const int qt = blk & 7, h = (blk >> 3) & 15, b = blk >> 7;
  const int tid = threadIdx.x, lane = tid & 63, wave = tid >> 6;
  const int lo = lane & 15, g = lane >> 4;
  const int qr0 = qt * 256 + wave * 32;
  // two Q fragment pairs: rows qr0+lo (A) and qr0+16+lo (B)
  const unsigned short* qrowA = qkv + (size_t)(b * SEQ + qr0 + lo) * 3072 + h * 64 + g * 8;
  const unsigned short* qrowB = qrowA + (size_t)16 * 3072;
  const short8 qA0 = *(const short8*)qrowA;
  const short8 qA1 = *(const short8*)(qrowA + 32);
  const short8 qB0 = *(const short8*)qrowB;
  const short8 qB1 = *(const short8*)(qrowB + 32);
  // cooperative staging: 512 threads x 16B = one 64x64 bf16 tile per array
  const int srow = tid >> 3, scol = (tid & 7) * 8;
  const unsigned short* gK = qkv + (size_t)(b * SEQ + srow) * 3072 + 1024 + h * 64 + scol;
  const unsigned short* gV = vt + ((size_t)((b * NHEADS + h) * DHEAD) + srow) * SEQ + scol;
  short8 rk = *(const short8*)gK;
  short8 rv = *(const short8*)gV;
  *(short8*)&lK[0][srow * LDT + scol] = rk;
  *(short8*)&lV[0][srow * LDT + scol] = rv;
  f32x4 oA[4] = {}, oB[4] = {};
  float mA = -1e30f, lA_ = 0.f, mB = -1e30f, lB_ = 0.f;
  const f32x4 fzero = {};
  unsigned short* PbA = &pP[wave][0];
  unsigned short* PbB = &pP[8 + wave][0];
  constexpr int NT = SEQ / 64;
  for (int t = 0; t < NT; ++t) {
    __syncthreads();  // staged writes for tile t visible; all waves done with tile t-1
    const unsigned short* Kb = &lK[t & 1][0];
    const unsigned short* Vb = &lV[t & 1][0];
    if (t + 1 < NT) {  // issue next-tile global loads; consumed at loop bottom
      rk = *(const short8*)(gK + (size_t)(t + 1) * 64 * 3072);
      rv = *(const short8*)(gV + (t + 1) * 64);
    }
    // QK^T (swapped): s*[jt][r] = S[k = jt*16+g*4+r][q = lo] ; K frags shared by both halves
    f32x4 sA[4], sB[4];
    __builtin_amdgcn_s_setprio(1);
#pragma unroll
    for (int jt = 0; jt < 4; ++jt) {
      short8 kf0 = *(const short8*)(Kb + (jt * 16 + lo) * LDT + g * 8);
      short8 kf1 = *(const short8*)(Kb + (jt * 16 + lo) * LDT + 32 + g * 8);
      sA[jt] = MFMA_BF16(kf1, qA1, MFMA_BF16(kf0, qA0, fzero));
      sB[jt] = MFMA_BF16(kf1, qB1, MFMA_BF16(kf0, qB0, fzero));
    }
    __builtin_amdgcn_s_setprio(0);
    // tile maxes (log2 units), 16 in-reg + xor-16/32 per half
    float tA0 = fmaxf(fmaxf(sA[0][0], sA[0][1]), fmaxf(sA[0][2], sA[0][3]));
    float tA1 = fmaxf(fmaxf(sA[1][0], sA[1][1]), fmaxf(sA[1][2], sA[1][3]));
    float tA2 = fmaxf(fmaxf(sA[2][0], sA[2][1]), fmaxf(sA[2][2], sA[2][3]));
    float tA3 = fmaxf(fmaxf(sA[3][0], sA[3][1]), fmaxf(sA[3][2], sA[3][3]));
    float mxA = fmaxf(fmaxf(tA0, tA1), fmaxf(tA2, tA3));
    float tB0 = fmaxf(fmaxf(sB[0][0], sB[0][1]), fmaxf(sB[0][2], sB[0][3]));
    float tB1 = fmaxf(fmaxf(sB[1][0], sB[1][1]), fmaxf(sB[1][2], sB[1][3]));
    float tB2 = fmaxf(fmaxf(sB[2][0], sB[2][1]), fmaxf(sB[2][2], sB[2][3]));
    float tB3 = fmaxf(fmaxf(sB[3][0], sB[3][1]), fmaxf(sB[3][2], sB[3][3]));
    float mxB = fmaxf(fmaxf(tB0, tB1), fmaxf(tB2, tB3));
    mxA = fmaxf(mxA, __shfl_xor(mxA, 16));
    mxA = fmaxf(mxA, __shfl_xor(mxA, 32));
    mxB = fmaxf(mxB, __shfl_xor(mxB, 16));
    mxB = fmaxf(mxB, __shfl_xor(mxB, 32));
    // defer-max (threshold 11 bits ~ e^7.6); wave-uniform branch
    if (!__all((mxA <= mA + 11.0f) && (mxB <= mB + 11.0f))) {
      const float mnA = fmaxf(mA, mxA), mnB = fmaxf(mB, mxB);
      const float aA = exp2f(mA - mnA), aB = exp2f(mB - mnB);
      mA = mnA; mB = mnB;
      lA_ *= aA; lB_ *= aB;
#pragma unroll
      for (int c = 0; c < 4; ++c)
#pragma unroll
        for (int r = 0; r < 4; ++r) { oA[c][r] *= aA; oB[c][r] *= aB; }
    }
    float psA = 0.f, psB = 0.f;
#pragma unroll
    for (int jt = 0; jt < 4; ++jt) {
      float a0 = exp2f(sA[jt][0] - mA), a1 = exp2f(sA[jt][1] - mA);
      float a2 = exp2f(sA[jt][2] - mA), a3 = exp2f(sA[jt][3] - mA);
      sA[jt][0] = a0; sA[jt][1] = a1; sA[jt][2] = a2; sA[jt][3] = a3;
      psA += (a0 + a1) + (a2 + a3);
      float b0 = exp2f(sB[jt][0] - mB), b1 = exp2f(sB[jt][1] - mB);
      float b2 = exp2f(sB[jt][2] - mB), b3 = exp2f(sB[jt][3] - mB);
      sB[jt][0] = b0; sB[jt][1] = b1; sB[jt][2] = b2; sB[jt][3] = b3;
      psB += (b0 + b1) + (b2 + b3);
    }
    lA_ += psA;
    lB_ += psB;
    // P -> packed bf16 -> wave-private strips (row = q = lo), b32 writes
#pragma unroll
    for (int jt = 0; jt < 4; ++jt) {
      *(unsigned*)(PbA + lo * LDP + jt * 16 + g * 4) = cvt_pk_bf16(sA[jt][0], sA[jt][1]);
      *(unsigned*)(PbA + lo * LDP + jt * 16 + g * 4 + 2) = cvt_pk_bf16(sA[jt][2], sA[jt][3]);
      *(unsigned*)(PbB + lo * LDP + jt * 16 + g * 4) = cvt_pk_bf16(sB[jt][0], sB[jt][1]);
      *(unsigned*)(PbB + lo * LDP + jt * 16 + g * 4 + 2) = cvt_pk_bf16(sB[jt][2], sB[jt][3]);
    }
    // P fragments (B-operand): lane holds P[q=lo][k = g*8.. , +32]
    short8 pA0 = *(const short8*)(PbA + lo * LDP + g * 8);
    short8 pA1 = *(const short8*)(PbA + lo * LDP + 32 + g * 8);
    short8 pB0 = *(const short8*)(PbB + lo * LDP + g * 8);
    short8 pB1 = *(const short8*)(PbB + lo * LDP + 32 + g * 8);
    // PV (swapped): o*[c][r] = O[q=lo][d = c*16+g*4+r] ; V frags shared by both halves
    __builtin_amdgcn_s_setprio(1);
#pragma unroll
    for (int c = 0; c < 4; ++c) {
      short8 vb0 = *(const short8*)(Vb + (c * 16 + lo) * LDT + g * 8);
      short8 vb1 = *(const short8*)(Vb + (c * 16 + lo) * LDT + 32 + g * 8);
      oA[c] = MFMA_BF16(vb1, pA1, MFMA_BF16(vb0, pA0, oA[c]));
      oB[c] = MFMA_BF16(vb1, pB1, MFMA_BF16(vb0, pB0, oB[c]));
    }
    __builtin_amdgcn_s_setprio(0);
    if (t + 1 < NT) {  // write prefetched tile into the other buffer
      *(short8*)&lK[(t + 1) & 1][srow * LDT + scol] = rk;
      *(short8*)&lV[(t + 1) & 1][srow * LDT + scol] = rv;
    }
  }
  // deferred cross-g sum reduction, normalize, packed stores
  lA_ += __shfl_xor(lA_, 16);
  lA_ += __shfl_xor(lA_, 32);
  lB_ += __shfl_xor(lB_, 16);
  lB_ += __shfl_xor(lB_, 32);
  const float rA = 1.0f / lA_, rB = 1.0f / lB_;
  unsigned short* orowA = out + (size_t)(b * SEQ + qr0 + lo) * D_MODEL + h * 64 + g * 4;
  unsigned short* orowB = orowA + (size_t)16 * D_MODEL;
#pragma unroll
  for (int c = 0; c < 4; ++c)
#pragma unroll
    for (int r = 0; r < 4; r += 2) {
      *(unsigned*)(orowA + c * 16 + r) = cvt_pk_bf16(oA[c][r] * rA, oA[c][r + 1] * rA);
      *(unsigned*)(orowB + c * 16 + r) = cvt_pk_bf16(oB[c][r] * rB, oB[c][r + 1] * rB);
    }
}

// ---------------- host launch ----------------
extern "C" void kernel_launch(void* const* d_in, const int* in_sizes, int n_in, void* d_out,
                              int out_size, void* d_ws, size_t ws_size, hipStream_t stream) {
  const float* x = (const float*)d_in[0];
  const float* w_qkv = (const float*)d_in[1];
  const float* w_out = (const float*)d_in[2];
  const float* w_ffn1 = (const float*)d_in[3];
  const float* w_ffn2 = (const float*)d_in[4];
  const float* g1 = (const float*)d_in[5];
  const float* b1 = (const float*)d_in[6];
  const float* g2 = (const float*)d_in[7];
  const float* b2 = (const float*)d_in[8];
  const float* temp = (const float*)d_in[9];
  float* outp = (float*)d_out;

  char* ws = (char*)d_ws;
  size_t off = 0;
  auto alloc = [&](size_t bytes) {
    void* p = ws + off;
    off += (bytes + 255) & ~(size_t)255;
    return p;
  };
  unsigned short* wqkv_bf = (unsigned short*)alloc((size_t)3072 * 1024 * 2);
  unsigned short* wout_bf = (unsigned short*)alloc((size_t)1024 * 1024 * 2);
  unsigned short* wf1_bf = (unsigned short*)alloc((size_t)2048 * 1024 * 2);
  unsigned short* wf2_bf = (unsigned short*)alloc((size_t)1024 * 2048 * 2);
  unsigned short* h_bf = (unsigned short*)alloc((size_t)MTOK * 1024 * 2);   // reused for h2
  unsigned short* qkv_bf = (unsigned short*)alloc((size_t)MTOK * 3072 * 2); // reused for ffn1 out
  unsigned short* vt_bf = (unsigned short*)alloc((size_t)BATCH * NHEADS * DHEAD * SEQ * 2);
  unsigned short* ao_bf = (unsigned short*)alloc((size_t)MTOK * 1024 * 2);
  float* x2 = (float*)alloc((size_t)MTOK * 1024 * 4);

  // weight conversions (single launch)
  f32_to_bf16_all<<<8192, 256, 0, stream>>>(w_qkv, w_out, w_ffn1, w_ffn2, wqkv_bf, wout_bf, wf1_bf,
                                            wf2_bf);
  // LN1
  ln_fwd<<<MTOK, 256, 0, stream>>>(x, g1, b1, h_bf);
  // qkv = h @ w_qkv^T
  gemm_bt2<0><<<dim3(3072 / 128, MTOK / 128), 256, 0, stream>>>(h_bf, wqkv_bf, nullptr,
                                                                (void*)qkv_bf, MTOK, 3072, 1024);
  // l2norm q (x log2e/temp), k; build Vt
  prep_qkv<<<BATCH * NHEADS * (SEQ / 64), 256, 0, stream>>>(qkv_bf, vt_bf, temp);
  // attention
  attn_fwd5<<<BATCH * NHEADS * (SEQ / 256), 512, 0, stream>>>(qkv_bf, vt_bf, ao_bf);
  // x2 = x + attn_out @ w_out^T
  gemm_bt2<1><<<dim3(1024 / 128, MTOK / 128), 256, 0, stream>>>(ao_bf, wout_bf, x, (void*)x2, MTOK,
                                                                1024, 1024);
  // LN2
  ln_fwd<<<MTOK, 256, 0, stream>>>(x2, g2, b2, h_bf);
  // ffn1 = relu(h2 @ w_ffn1^T)  (reuse qkv buffer)
  gemm_bt2<2><<<dim3(2048 / 128, MTOK / 128), 256, 0, stream>>>(h_bf, wf1_bf, nullptr,
                                                                (void*)qkv_bf, MTOK, 2048, 1024);
  // out = x2 + ffn1 @ w_ffn2^T
  gemm_bt2<1><<<dim3(1024 / 128, MTOK / 128), 256, 0, stream>>>(qkv_bf, wf2_bf, x2, (void*)outp,
                                                                MTOK, 1024, 2048);
}

// Round 6
// 378.724 us; speedup vs baseline: 1.0677x; 1.0342x over previous
//
#include <hip/hip_runtime.h>
#include <cstdint>
#include <cstddef>
#include <math.h>

typedef __attribute__((ext_vector_type(8))) short short8;
typedef __attribute__((ext_vector_type(4))) float f32x4;

#define D_MODEL 1024
#define NHEADS 16
#define DHEAD 64
#define BATCH 4
#define SEQ 2048
#define MTOK (BATCH * SEQ)

__device__ __forceinline__ unsigned short f2bf(float f) {
  union { float f; unsigned u; } v; v.f = f;
  unsigned r = v.u + 0x7fffu + ((v.u >> 16) & 1u);
  return (unsigned short)(r >> 16);
}
__device__ __forceinline__ float bf2f(unsigned short u) {
  union { unsigned u; float f; } v; v.u = ((unsigned)u) << 16;
  return v.f;
}
__device__ __forceinline__ unsigned cvt_pk_bf16(float a, float b) {
  unsigned u;
  asm("v_cvt_pk_bf16_f32 %0, %1, %2" : "=v"(u) : "v"(a), "v"(b));
  return u;
}

typedef const __attribute__((address_space(1))) unsigned int* gas1_t;
typedef __attribute__((address_space(3))) unsigned int* las3_t;
// async global->LDS, 16B per lane; LDS dest must be wave-uniform base (HW adds lane*16B)
__device__ __forceinline__ void gload16(const unsigned short* g, unsigned short* l) {
  __builtin_amdgcn_global_load_lds((gas1_t)g, (las3_t)l, 16, 0, 0);
}

#define MFMA_BF16(a, b, c) __builtin_amdgcn_mfma_f32_16x16x32_bf16(a, b, c, 0, 0, 0)

// ---------------- fp32 -> bf16 conversion, all 4 weights in one launch ----------------
__global__ __launch_bounds__(256) void f32_to_bf16_all(const float* __restrict__ s0,
                                                       const float* __restrict__ s1,
                                                       const float* __restrict__ s2,
                                                       const float* __restrict__ s3,
                                                       unsigned short* __restrict__ d0,
                                                       unsigned short* __restrict__ d1,
                                                       unsigned short* __restrict__ d2,
                                                       unsigned short* __restrict__ d3) {
  int j = blockIdx.x * 256 + threadIdx.x;  // float4 index over concatenated ranges
  const float* s;
  unsigned short* d;
  if (j < 786432) { s = s0; d = d0; }
  else if ((j -= 786432) < 262144) { s = s1; d = d1; }
  else if ((j -= 262144) < 524288) { s = s2; d = d2; }
  else { j -= 524288; s = s3; d = d3; }
  float4 v = ((const float4*)s)[j];
  ushort4 o;
  o.x = f2bf(v.x); o.y = f2bf(v.y); o.z = f2bf(v.z); o.w = f2bf(v.w);
  ((ushort4*)d)[j] = o;
}

// ---------------- LayerNorm: fp32 in -> bf16 out ----------------
__global__ __launch_bounds__(256) void ln_fwd(const float* __restrict__ x, const float* __restrict__ g,
                                              const float* __restrict__ b,
                                              unsigned short* __restrict__ out) {
  const int row = blockIdx.x, t = threadIdx.x;
  float4 v = *(const float4*)(x + (size_t)row * D_MODEL + t * 4);
  float s = v.x + v.y + v.z + v.w;
  float s2 = v.x * v.x + v.y * v.y + v.z * v.z + v.w * v.w;
#pragma unroll
  for (int m = 1; m < 64; m <<= 1) { s += __shfl_xor(s, m); s2 += __shfl_xor(s2, m); }
  __shared__ float red[8];
  int wv = t >> 6;
  if ((t & 63) == 0) { red[wv] = s; red[4 + wv] = s2; }
  __syncthreads();
  s = red[0] + red[1] + red[2] + red[3];
  s2 = red[4] + red[5] + red[6] + red[7];
  float mu = s * (1.f / D_MODEL);
  float var = s2 * (1.f / D_MODEL) - mu * mu;
  float rs = rsqrtf(var + 1e-5f);
  float4 gg = *(const float4*)(g + t * 4);
  float4 bb = *(const float4*)(b + t * 4);
  ushort4 o;
  o.x = f2bf((v.x - mu) * rs * gg.x + bb.x);
  o.y = f2bf((v.y - mu) * rs * gg.y + bb.y);
  o.z = f2bf((v.z - mu) * rs * gg.z + bb.z);
  o.w = f2bf((v.w - mu) * rs * gg.w + bb.w);
  *(ushort4*)(out + (size_t)row * D_MODEL + t * 4) = o;
}

// ---------------- GEMM (m97 structure): C[M,N] = A[M,K] * B[N,K]^T ----------------
// EPI: 0 bf16, 1 fp32 R+acc, 2 bf16 relu(acc),
//      3 qkv-fused: per-head l2norm of q,k rows (q also x log2e/T), v plain bf16.
template <int EPI>
__global__ __launch_bounds__(256) void gemm_bt2(const unsigned short* __restrict__ A,
                                                const unsigned short* __restrict__ B,
                                                const float* __restrict__ R,
                                                const float* __restrict__ Tptr,
                                                void* __restrict__ Cout, int M, int N, int K) {
  constexpr int BM = 128, BN = 128, BK = 32;
  __shared__ unsigned short lA[2][BM * BK], lB[2][BN * BK];
  const int tid = threadIdx.x, lane = tid & 63, wave = tid >> 6;
  const int lo = lane & 15, g = lane >> 4;
  const int bm = blockIdx.y * BM, bn = blockIdx.x * BN;
  const int wr = wave >> 1, wc = wave & 1;
  f32x4 acc[4][4] = {};
  const int c0 = wave * 128 + lane, c1 = c0 + 64;
  const unsigned short* gA0 = A + (size_t)(bm + (c0 >> 2)) * K + (c0 & 3) * 8;
  const unsigned short* gA1 = A + (size_t)(bm + (c1 >> 2)) * K + (c1 & 3) * 8;
  const unsigned short* gB0 = B + (size_t)(bn + (c0 >> 2)) * K + (c0 & 3) * 8;
  const unsigned short* gB1 = B + (size_t)(bn + (c1 >> 2)) * K + (c1 & 3) * 8;
  const int nk = K / BK;
  auto stage = [&](int buf, int kt) {
    const size_t ko = (size_t)kt * BK;
    gload16(gA0 + ko, &lA[buf][(wave * 128) * 8]);
    gload16(gA1 + ko, &lA[buf][(wave * 128 + 64) * 8]);
    gload16(gB0 + ko, &lB[buf][(wave * 128) * 8]);
    gload16(gB1 + ko, &lB[buf][(wave * 128 + 64) * 8]);
  };
  stage(0, 0);
  for (int kt = 0; kt < nk; ++kt) {
    __syncthreads();
    if (kt + 1 < nk) stage((kt + 1) & 1, kt + 1);
    const unsigned short* La = &lA[kt & 1][0];
    const unsigned short* Lb = &lB[kt & 1][0];
    short8 af[4], bfr[4];
#pragma unroll
    for (int m = 0; m < 4; ++m)
      af[m] = *(const short8*)(La + (wr * 64 + m * 16 + lo) * BK + g * 8);
#pragma unroll
    for (int n = 0; n < 4; ++n)
      bfr[n] = *(const short8*)(Lb + (wc * 64 + n * 16 + lo) * BK + g * 8);
#pragma unroll
    for (int m = 0; m < 4; ++m)
#pragma unroll
      for (int n = 0; n < 4; ++n) acc[m][n] = MFMA_BF16(af[m], bfr[n], acc[m][n]);
  }
  const int r0 = bm + wr * 64 + g * 4;
  const int c0c = bn + wc * 64 + lo;
  if (EPI == 3) {
    // this wave's 64 output columns are exactly one head-slice of q, k, or v
    const int hb = bn + wc * 64;
    const bool isq = hb < 1024, isk = (hb >= 1024) && (hb < 2048);
    const float qs = 1.44269504088896f / Tptr[0];  // log2(e)/T folded into q
#pragma unroll
    for (int m = 0; m < 4; ++m)
#pragma unroll
      for (int r = 0; r < 4; ++r) {
        float sc = 1.0f;
        if (isq || isk) {
          float ss = 0.f;
#pragma unroll
          for (int n = 0; n < 4; ++n) ss += acc[m][n][r] * acc[m][n][r];
          ss += __shfl_xor(ss, 1);
          ss += __shfl_xor(ss, 2);
          ss += __shfl_xor(ss, 4);
          ss += __shfl_xor(ss, 8);  // full head-dim sum across the 16 lo-lanes
          sc = 1.0f / fmaxf(sqrtf(ss), 1e-12f);
          if (isq) sc *= qs;
        }
#pragma unroll
        for (int n = 0; n < 4; ++n) {
          size_t off = (size_t)(r0 + m * 16 + r) * N + (c0c + n * 16);
          ((unsigned short*)Cout)[off] = f2bf(acc[m][n][r] * sc);
        }
      }
  } else {
#pragma unroll
    for (int m = 0; m < 4; ++m)
#pragma unroll
      for (int n = 0; n < 4; ++n) {
#pragma unroll
        for (int r = 0; r < 4; ++r) {
          size_t off = (size_t)(r0 + m * 16 + r) * N + (c0c + n * 16);
          float v = acc[m][n][r];
          if (EPI == 0) ((unsigned short*)Cout)[off] = f2bf(v);
          else if (EPI == 1) ((float*)Cout)[off] = R[off] + v;
          else ((unsigned short*)Cout)[off] = f2bf(fmaxf(v, 0.f));
        }
      }
  }
}

// ---------------- transpose v -> Vt[b,h,d,n] (q,k already normalized in GEMM epilogue) ----------------
__global__ __launch_bounds__(256) void transpose_v(const unsigned short* __restrict__ qkv,
                                                   unsigned short* __restrict__ vt) {
  __shared__ unsigned short tile[64][80];
  const int blk = blockIdx.x;
  const int ntile = blk & 31, h = (blk >> 5) & 15, b = blk >> 9;
  const int t = threadIdx.x;
  const int tt = t >> 2, c4 = t & 3;
  size_t rowbase = (size_t)(b * SEQ + ntile * 64 + tt) * 3072 + h * 64 + c4 * 16;
  const unsigned short* pv = qkv + rowbase + 2048;
  *(short8*)&tile[tt][c4 * 16] = *(const short8*)pv;
  *(short8*)&tile[tt][c4 * 16 + 8] = *(const short8*)(pv + 8);
  __syncthreads();
  const int d = tt;
  short8 o0, o1;
#pragma unroll
  for (int j = 0; j < 8; ++j) o0[j] = (short)tile[c4 * 16 + j][d];
#pragma unroll
  for (int j = 0; j < 8; ++j) o1[j] = (short)tile[c4 * 16 + 8 + j][d];
  size_t vr = (size_t)((b * NHEADS + h) * DHEAD + d) * SEQ + ntile * 64 + c4 * 16;
  *(short8*)(vt + vr) = o0;
  *(short8*)(vt + vr + 8) = o1;
}

// ---------------- flash attention v6: static-max softmax (cosine bound) ----------------
// Scores are bounded: s = (q^.k^)*(log2e/T) <= M0. The MFMA accumulator is initialized to
// -M0, so P = exp2(s) directly -- no online max, no rescale, no max shuffles, ever.
__global__ __launch_bounds__(512) void attn_fwd6(const unsigned short* __restrict__ qkv,
                                                 const unsigned short* __restrict__ vt,
                                                 unsigned short* __restrict__ out,
                                                 const float* __restrict__ temp) {
  constexpr int LDT = 72;  // K/V LDS row stride (shorts)
  constexpr int LDP = 66;  // P strip row stride (shorts)
  __shared__ unsigned short lK[2][64 * LDT];
  __shared__ unsigned short lV[2][64 * LDT];
  __shared__ unsigned short pP[16][16 * LDP];  // 2 strips per wave
  const int blk = blockIdx.x;
  const int qt = blk & 7, h = (blk >> 3) & 15, b = blk >> 7;
  const int tid = threadIdx.x, lane = tid & 63, wave = tid >> 6;
  const int lo = lane & 15, g = lane >> 4;
  const int qr0 = qt * 256 + wave * 32;
  const float M0 = 1.05f * 1.44269504088896f / temp[0];  // bound on folded scores
  const f32x4 minit = {-M0, -M0, -M0, -M0};
  // two Q fragment pairs: rows qr0+lo (A) and qr0+16+lo (B)
  const unsigned short* qrowA = qkv + (size_t)(b * SEQ + qr0 + lo) * 3072 + h * 64 + g * 8;
  const unsigned short* qrowB = qrowA + (size_t)16 * 3072;
  const short8 qA0 = *(const short8*)qrowA;
  const short8 qA1 = *(const short8*)(qrowA + 32);
  const short8 qB0 = *(const short8*)qrowB;
  const short8 qB1 = *(const short8*)(qrowB + 32);
  // cooperative staging: 512 threads x 16B = one 64x64 bf16 tile per array
  const int srow = tid >> 3, scol = (tid & 7) * 8;
  const unsigned short* gK = qkv + (size_t)(b * SEQ + srow) * 3072 + 1024 + h * 64 + scol;
  const unsigned short* gV = vt + ((size_t)((b * NHEADS + h) * DHEAD) + srow) * SEQ + scol;
  short8 rk = *(const short8*)gK;
  short8 rv = *(const short8*)gV;
  *(short8*)&lK[0][srow * LDT + scol] = rk;
  *(short8*)&lV[0][srow * LDT + scol] = rv;
  f32x4 oA[4] = {}, oB[4] = {};
  float lA_ = 0.f, lB_ = 0.f;
  unsigned short* PbA = &pP[wave][0];
  unsigned short* PbB = &pP[8 + wave][0];
  constexpr int NT = SEQ / 64;
  for (int t = 0; t < NT; ++t) {
    __syncthreads();  // staged writes for tile t visible; all waves done with tile t-1
    const unsigned short* Kb = &lK[t & 1][0];
    const unsigned short* Vb = &lV[t & 1][0];
    if (t + 1 < NT) {  // issue next-tile global loads; consumed at loop bottom
      rk = *(const short8*)(gK + (size_t)(t + 1) * 64 * 3072);
      rv = *(const short8*)(gV + (t + 1) * 64);
    }
    // QK^T (swapped): s*[jt][r] = S[k = jt*16+g*4+r][q = lo] - M0 (C-init)
    f32x4 sA[4], sB[4];
    __builtin_amdgcn_s_setprio(1);
#pragma unroll
    for (int jt = 0; jt < 4; ++jt) {
      short8 kf0 = *(const short8*)(Kb + (jt * 16 + lo) * LDT + g * 8);
      short8 kf1 = *(const short8*)(Kb + (jt * 16 + lo) * LDT + 32 + g * 8);
      sA[jt] = MFMA_BF16(kf1, qA1, MFMA_BF16(kf0, qA0, minit));
      sB[jt] = MFMA_BF16(kf1, qB1, MFMA_BF16(kf0, qB0, minit));
    }
    __builtin_amdgcn_s_setprio(0);
    // static-max softmax: P = exp2(s) directly; lane-partial sums, reduced once at the end
    float psA = 0.f, psB = 0.f;
#pragma unroll
    for (int jt = 0; jt < 4; ++jt) {
      float a0 = exp2f(sA[jt][0]), a1 = exp2f(sA[jt][1]);
      float a2 = exp2f(sA[jt][2]), a3 = exp2f(sA[jt][3]);
      sA[jt][0] = a0; sA[jt][1] = a1; sA[jt][2] = a2; sA[jt][3] = a3;
      psA += (a0 + a1) + (a2 + a3);
      float b0 = exp2f(sB[jt][0]), b1 = exp2f(sB[jt][1]);
      float b2 = exp2f(sB[jt][2]), b3 = exp2f(sB[jt][3]);
      sB[jt][0] = b0; sB[jt][1] = b1; sB[jt][2] = b2; sB[jt][3] = b3;
      psB += (b0 + b1) + (b2 + b3);
    }
    lA_ += psA;
    lB_ += psB;
    // P -> packed bf16 -> wave-private strips (row = q = lo), b32 writes
#pragma unroll
    for (int jt = 0; jt < 4; ++jt) {
      *(unsigned*)(PbA + lo * LDP + jt * 16 + g * 4) = cvt_pk_bf16(sA[jt][0], sA[jt][1]);
      *(unsigned*)(PbA + lo * LDP + jt * 16 + g * 4 + 2) = cvt_pk_bf16(sA[jt][2], sA[jt][3]);
      *(unsigned*)(PbB + lo * LDP + jt * 16 + g * 4) = cvt_pk_bf16(sB[jt][0], sB[jt][1]);
      *(unsigned*)(PbB + lo * LDP + jt * 16 + g * 4 + 2) = cvt_pk_bf16(sB[jt][2], sB[jt][3]);
    }
    // P fragments (B-operand): lane holds P[q=lo][k = g*8.. , +32]
    short8 pA0 = *(const short8*)(PbA + lo * LDP + g * 8);
    short8 pA1 = *(const short8*)(PbA + lo * LDP + 32 + g * 8);
    short8 pB0 = *(const short8*)(PbB + lo * LDP + g * 8);
    short8 pB1 = *(const short8*)(PbB + lo * LDP + 32 + g * 8);
    // PV (swapped): o*[c][r] = O[q=lo][d = c*16+g*4+r] ; V frags shared by both halves
    __builtin_amdgcn_s_setprio(1);
#pragma unroll
    for (int c = 0; c < 4; ++c) {
      short8 vb0 = *(const short8*)(Vb + (c * 16 + lo) * LDT + g * 8);
      short8 vb1 = *(const short8*)(Vb + (c * 16 + lo) * LDT + 32 + g * 8);
      oA[c] = MFMA_BF16(vb1, pA1, MFMA_BF16(vb0, pA0, oA[c]));
      oB[c] = MFMA_BF16(vb1, pB1, MFMA_BF16(vb0, pB0, oB[c]));
    }
    __builtin_amdgcn_s_setprio(0);
    if (t + 1 < NT) {  // write prefetched tile into the other buffer
      *(short8*)&lK[(t + 1) & 1][srow * LDT + scol] = rk;
      *(short8*)&lV[(t + 1) & 1][srow * LDT + scol] = rv;
    }
  }
  // deferred cross-g sum reduction, normalize, packed stores
  lA_ += __shfl_xor(lA_, 16);
  lA_ += __shfl_xor(lA_, 32);
  lB_ += __shfl_xor(lB_, 16);
  lB_ += __shfl_xor(lB_, 32);
  const float rA = 1.0f / lA_, rB = 1.0f / lB_;
  unsigned short* orowA = out + (size_t)(b * SEQ + qr0 + lo) * D_MODEL + h * 64 + g * 4;
  unsigned short* orowB = orowA + (size_t)16 * D_MODEL;
#pragma unroll
  for (int c = 0; c < 4; ++c)
#pragma unroll
    for (int r = 0; r < 4; r += 2) {
      *(unsigned*)(orowA + c * 16 + r) = cvt_pk_bf16(oA[c][r] * rA, oA[c][r + 1] * rA);
      *(unsigned*)(orowB + c * 16 + r) = cvt_pk_bf16(oB[c][r] * rB, oB[c][r + 1] * rB);
    }
}

// ---------------- host launch ----------------
extern "C" void kernel_launch(void* const* d_in, const int* in_sizes, int n_in, void* d_out,
                              int out_size, void* d_ws, size_t ws_size, hipStream_t stream) {
  const float* x = (const float*)d_in[0];
  const float* w_qkv = (const float*)d_in[1];
  const float* w_out = (const float*)d_in[2];
  const float* w_ffn1 = (const float*)d_in[3];
  const float* w_ffn2 = (const float*)d_in[4];
  const float* g1 = (const float*)d_in[5];
  const float* b1 = (const float*)d_in[6];
  const float* g2 = (const float*)d_in[7];
  const float* b2 = (const float*)d_in[8];
  const float* temp = (const float*)d_in[9];
  float* outp = (float*)d_out;

  char* ws = (char*)d_ws;
  size_t off = 0;
  auto alloc = [&](size_t bytes) {
    void* p = ws + off;
    off += (bytes + 255) & ~(size_t)255;
    return p;
  };
  unsigned short* wqkv_bf = (unsigned short*)alloc((size_t)3072 * 1024 * 2);
  unsigned short* wout_bf = (unsigned short*)alloc((size_t)1024 * 1024 * 2);
  unsigned short* wf1_bf = (unsigned short*)alloc((size_t)2048 * 1024 * 2);
  unsigned short* wf2_bf = (unsigned short*)alloc((size_t)1024 * 2048 * 2);
  unsigned short* h_bf = (unsigned short*)alloc((size_t)MTOK * 1024 * 2);   // reused for h2
  unsigned short* qkv_bf = (unsigned short*)alloc((size_t)MTOK * 3072 * 2); // reused for ffn1 out
  unsigned short* vt_bf = (unsigned short*)alloc((size_t)BATCH * NHEADS * DHEAD * SEQ * 2);
  unsigned short* ao_bf = (unsigned short*)alloc((size_t)MTOK * 1024 * 2);
  float* x2 = (float*)alloc((size_t)MTOK * 1024 * 4);

  // weight conversions (single launch)
  f32_to_bf16_all<<<8192, 256, 0, stream>>>(w_qkv, w_out, w_ffn1, w_ffn2, wqkv_bf, wout_bf, wf1_bf,
                                            wf2_bf);
  // LN1
  ln_fwd<<<MTOK, 256, 0, stream>>>(x, g1, b1, h_bf);
  // qkv = h @ w_qkv^T with fused per-head l2norm of q (x log2e/T) and k
  gemm_bt2<3><<<dim3(3072 / 128, MTOK / 128), 256, 0, stream>>>(h_bf, wqkv_bf, nullptr, temp,
                                                                (void*)qkv_bf, MTOK, 3072, 1024);
  // build Vt
  transpose_v<<<BATCH * NHEADS * (SEQ / 64), 256, 0, stream>>>(qkv_bf, vt_bf);
  // attention (static-max softmax)
  attn_fwd6<<<BATCH * NHEADS * (SEQ / 256), 512, 0, stream>>>(qkv_bf, vt_bf, ao_bf, temp);
  // x2 = x + attn_out @ w_out^T
  gemm_bt2<1><<<dim3(1024 / 128, MTOK / 128), 256, 0, stream>>>(ao_bf, wout_bf, x, nullptr,
                                                                (void*)x2, MTOK, 1024, 1024);
  // LN2
  ln_fwd<<<MTOK, 256, 0, stream>>>(x2, g2, b2, h_bf);
  // ffn1 = relu(h2 @ w_ffn1^T)  (reuse qkv buffer)
  gemm_bt2<2><<<dim3(2048 / 128, MTOK / 128), 256, 0, stream>>>(h_bf, wf1_bf, nullptr, nullptr,
                                                                (void*)qkv_bf, MTOK, 2048, 1024);
  // out = x2 + ffn1 @ w_ffn2^T
  gemm_bt2<1><<<dim3(1024 / 128, MTOK / 128), 256, 0, stream>>>(qkv_bf, wf2_bf, x2, nullptr,
                                                                (void*)outp, MTOK, 1024, 2048);
}

// Round 7
// 367.771 us; speedup vs baseline: 1.0995x; 1.0298x over previous
//
#include <hip/hip_runtime.h>
#include <cstdint>
#include <cstddef>
#include <math.h>

typedef __attribute__((ext_vector_type(8))) short short8;
typedef __attribute__((ext_vector_type(4))) float f32x4;

#define D_MODEL 1024
#define NHEADS 16
#define DHEAD 64
#define BATCH 4
#define SEQ 2048
#define MTOK (BATCH * SEQ)

__device__ __forceinline__ unsigned short f2bf(float f) {
  union { float f; unsigned u; } v; v.f = f;
  unsigned r = v.u + 0x7fffu + ((v.u >> 16) & 1u);
  return (unsigned short)(r >> 16);
}
__device__ __forceinline__ float bf2f(unsigned short u) {
  union { unsigned u; float f; } v; v.u = ((unsigned)u) << 16;
  return v.f;
}
__device__ __forceinline__ unsigned cvt_pk_bf16(float a, float b) {
  unsigned u;
  asm("v_cvt_pk_bf16_f32 %0, %1, %2" : "=v"(u) : "v"(a), "v"(b));
  return u;
}

typedef const __attribute__((address_space(1))) unsigned int* gas1_t;
typedef __attribute__((address_space(3))) unsigned int* las3_t;
// async global->LDS, 16B per lane; LDS dest must be wave-uniform base (HW adds lane*16B)
__device__ __forceinline__ void gload16(const unsigned short* g, unsigned short* l) {
  __builtin_amdgcn_global_load_lds((gas1_t)g, (las3_t)l, 16, 0, 0);
}

#define MFMA_BF16(a, b, c) __builtin_amdgcn_mfma_f32_16x16x32_bf16(a, b, c, 0, 0, 0)

// ---------------- fp32 -> bf16 conversion, all 4 weights in one launch ----------------
__global__ __launch_bounds__(256) void f32_to_bf16_all(const float* __restrict__ s0,
                                                       const float* __restrict__ s1,
                                                       const float* __restrict__ s2,
                                                       const float* __restrict__ s3,
                                                       unsigned short* __restrict__ d0,
                                                       unsigned short* __restrict__ d1,
                                                       unsigned short* __restrict__ d2,
                                                       unsigned short* __restrict__ d3) {
  int j = blockIdx.x * 256 + threadIdx.x;  // float4 index over concatenated ranges
  const float* s;
  unsigned short* d;
  if (j < 786432) { s = s0; d = d0; }
  else if ((j -= 786432) < 262144) { s = s1; d = d1; }
  else if ((j -= 262144) < 524288) { s = s2; d = d2; }
  else { j -= 524288; s = s3; d = d3; }
  float4 v = ((const float4*)s)[j];
  ushort4 o;
  o.x = f2bf(v.x); o.y = f2bf(v.y); o.z = f2bf(v.z); o.w = f2bf(v.w);
  ((ushort4*)d)[j] = o;
}

// ---------------- LayerNorm: fp32 in -> bf16 out ----------------
__global__ __launch_bounds__(256) void ln_fwd(const float* __restrict__ x, const float* __restrict__ g,
                                              const float* __restrict__ b,
                                              unsigned short* __restrict__ out) {
  const int row = blockIdx.x, t = threadIdx.x;
  float4 v = *(const float4*)(x + (size_t)row * D_MODEL + t * 4);
  float s = v.x + v.y + v.z + v.w;
  float s2 = v.x * v.x + v.y * v.y + v.z * v.z + v.w * v.w;
#pragma unroll
  for (int m = 1; m < 64; m <<= 1) { s += __shfl_xor(s, m); s2 += __shfl_xor(s2, m); }
  __shared__ float red[8];
  int wv = t >> 6;
  if ((t & 63) == 0) { red[wv] = s; red[4 + wv] = s2; }
  __syncthreads();
  s = red[0] + red[1] + red[2] + red[3];
  s2 = red[4] + red[5] + red[6] + red[7];
  float mu = s * (1.f / D_MODEL);
  float var = s2 * (1.f / D_MODEL) - mu * mu;
  float rs = rsqrtf(var + 1e-5f);
  float4 gg = *(const float4*)(g + t * 4);
  float4 bb = *(const float4*)(b + t * 4);
  ushort4 o;
  o.x = f2bf((v.x - mu) * rs * gg.x + bb.x);
  o.y = f2bf((v.y - mu) * rs * gg.y + bb.y);
  o.z = f2bf((v.z - mu) * rs * gg.z + bb.z);
  o.w = f2bf((v.w - mu) * rs * gg.w + bb.w);
  *(ushort4*)(out + (size_t)row * D_MODEL + t * 4) = o;
}

// ---------------- GEMM (m97 structure): C[M,N] = A[M,K] * B[N,K]^T ----------------
// XCD-chunked block swizzle: each XCD gets a contiguous chunk of (by,bx) work ->
// A row-panels stay L2-resident per XCD. Requires gridX*gridY % 8 == 0 (all our grids).
// EPI: 0 bf16, 1 fp32 R+acc, 2 bf16 relu(acc),
//      3 qkv-fused: per-head l2norm of q,k rows (q also x log2e/T), v plain bf16.
template <int EPI>
__global__ __launch_bounds__(256) void gemm_bt2(const unsigned short* __restrict__ A,
                                                const unsigned short* __restrict__ B,
                                                const float* __restrict__ R,
                                                const float* __restrict__ Tptr,
                                                void* __restrict__ Cout, int M, int N, int K) {
  constexpr int BM = 128, BN = 128, BK = 32;
  __shared__ unsigned short lA[2][BM * BK], lB[2][BN * BK];
  const int tid = threadIdx.x, lane = tid & 63, wave = tid >> 6;
  const int lo = lane & 15, g = lane >> 4;
  // XCD-aware remap of the linear workgroup id (dispatch round-robins id%8 across XCDs)
  const int nbx = gridDim.x;
  const int o = blockIdx.y * nbx + blockIdx.x;
  const int cpx = (nbx * gridDim.y) >> 3;
  const int w = (o & 7) * cpx + (o >> 3);
  const int bx = w % nbx, by = w / nbx;
  const int bm = by * BM, bn = bx * BN;
  const int wr = wave >> 1, wc = wave & 1;
  f32x4 acc[4][4] = {};
  const int c0 = wave * 128 + lane, c1 = c0 + 64;
  const unsigned short* gA0 = A + (size_t)(bm + (c0 >> 2)) * K + (c0 & 3) * 8;
  const unsigned short* gA1 = A + (size_t)(bm + (c1 >> 2)) * K + (c1 & 3) * 8;
  const unsigned short* gB0 = B + (size_t)(bn + (c0 >> 2)) * K + (c0 & 3) * 8;
  const unsigned short* gB1 = B + (size_t)(bn + (c1 >> 2)) * K + (c1 & 3) * 8;
  const int nk = K / BK;
  auto stage = [&](int buf, int kt) {
    const size_t ko = (size_t)kt * BK;
    gload16(gA0 + ko, &lA[buf][(wave * 128) * 8]);
    gload16(gA1 + ko, &lA[buf][(wave * 128 + 64) * 8]);
    gload16(gB0 + ko, &lB[buf][(wave * 128) * 8]);
    gload16(gB1 + ko, &lB[buf][(wave * 128 + 64) * 8]);
  };
  stage(0, 0);
  for (int kt = 0; kt < nk; ++kt) {
    __syncthreads();
    if (kt + 1 < nk) stage((kt + 1) & 1, kt + 1);
    const unsigned short* La = &lA[kt & 1][0];
    const unsigned short* Lb = &lB[kt & 1][0];
    short8 af[4], bfr[4];
#pragma unroll
    for (int m = 0; m < 4; ++m)
      af[m] = *(const short8*)(La + (wr * 64 + m * 16 + lo) * BK + g * 8);
#pragma unroll
    for (int n = 0; n < 4; ++n)
      bfr[n] = *(const short8*)(Lb + (wc * 64 + n * 16 + lo) * BK + g * 8);
#pragma unroll
    for (int m = 0; m < 4; ++m)
#pragma unroll
      for (int n = 0; n < 4; ++n) acc[m][n] = MFMA_BF16(af[m], bfr[n], acc[m][n]);
  }
  const int r0 = bm + wr * 64 + g * 4;
  const int c0c = bn + wc * 64 + lo;
  if (EPI == 3) {
    // this wave's 64 output columns are exactly one head-slice of q, k, or v
    const int hb = bn + wc * 64;
    const bool isq = hb < 1024, isk = (hb >= 1024) && (hb < 2048);
    const float qs = 1.44269504088896f / Tptr[0];  // log2(e)/T folded into q
#pragma unroll
    for (int m = 0; m < 4; ++m)
#pragma unroll
      for (int r = 0; r < 4; ++r) {
        float sc = 1.0f;
        if (isq || isk) {
          float ss = 0.f;
#pragma unroll
          for (int n = 0; n < 4; ++n) ss += acc[m][n][r] * acc[m][n][r];
          ss += __shfl_xor(ss, 1);
          ss += __shfl_xor(ss, 2);
          ss += __shfl_xor(ss, 4);
          ss += __shfl_xor(ss, 8);  // full head-dim sum across the 16 lo-lanes
          sc = 1.0f / fmaxf(sqrtf(ss), 1e-12f);
          if (isq) sc *= qs;
        }
#pragma unroll
        for (int n = 0; n < 4; ++n) {
          size_t off = (size_t)(r0 + m * 16 + r) * N + (c0c + n * 16);
          ((unsigned short*)Cout)[off] = f2bf(acc[m][n][r] * sc);
        }
      }
  } else {
#pragma unroll
    for (int m = 0; m < 4; ++m)
#pragma unroll
      for (int n = 0; n < 4; ++n) {
#pragma unroll
        for (int r = 0; r < 4; ++r) {
          size_t off = (size_t)(r0 + m * 16 + r) * N + (c0c + n * 16);
          float v = acc[m][n][r];
          if (EPI == 0) ((unsigned short*)Cout)[off] = f2bf(v);
          else if (EPI == 1) ((float*)Cout)[off] = R[off] + v;
          else ((unsigned short*)Cout)[off] = f2bf(fmaxf(v, 0.f));
        }
      }
  }
}

// ---------------- transpose v -> Vt[b,h,d,n] (q,k already normalized in GEMM epilogue) ----------------
__global__ __launch_bounds__(256) void transpose_v(const unsigned short* __restrict__ qkv,
                                                   unsigned short* __restrict__ vt) {
  __shared__ unsigned short tile[64][80];
  const int blk = blockIdx.x;
  const int ntile = blk & 31, h = (blk >> 5) & 15, b = blk >> 9;
  const int t = threadIdx.x;
  const int tt = t >> 2, c4 = t & 3;
  size_t rowbase = (size_t)(b * SEQ + ntile * 64 + tt) * 3072 + h * 64 + c4 * 16;
  const unsigned short* pv = qkv + rowbase + 2048;
  *(short8*)&tile[tt][c4 * 16] = *(const short8*)pv;
  *(short8*)&tile[tt][c4 * 16 + 8] = *(const short8*)(pv + 8);
  __syncthreads();
  const int d = tt;
  short8 o0, o1;
#pragma unroll
  for (int j = 0; j < 8; ++j) o0[j] = (short)tile[c4 * 16 + j][d];
#pragma unroll
  for (int j = 0; j < 8; ++j) o1[j] = (short)tile[c4 * 16 + 8 + j][d];
  size_t vr = (size_t)((b * NHEADS + h) * DHEAD + d) * SEQ + ntile * 64 + c4 * 16;
  *(short8*)(vt + vr) = o0;
  *(short8*)(vt + vr + 8) = o1;
}

// ---------------- flash attention v7: static-max softmax + XCD-local block mapping ----------------
// Block id d: bh = d & 63, qt = d >> 6  ->  d % 8 == bh % 8, so all 8 q-tiles sharing one
// (b,h)'s K/V land on the SAME XCD; per-XCD K/V working set = 8 heads x 512KB = L2 size.
__global__ __launch_bounds__(512) void attn_fwd7(const unsigned short* __restrict__ qkv,
                                                 const unsigned short* __restrict__ vt,
                                                 unsigned short* __restrict__ out,
                                                 const float* __restrict__ temp) {
  constexpr int LDT = 72;  // K/V LDS row stride (shorts)
  constexpr int LDP = 66;  // P strip row stride (shorts)
  __shared__ unsigned short lK[2][64 * LDT];
  __shared__ unsigned short lV[2][64 * LDT];
  __shared__ unsigned short pP[16][16 * LDP];  // 2 strips per wave
  const int d_ = blockIdx.x;
  const int bh = d_ & 63, qt = d_ >> 6;
  const int b = bh >> 4, h = bh & 15;
  const int tid = threadIdx.x, lane = tid & 63, wave = tid >> 6;
  const int lo = lane & 15, g = lane >> 4;
  const int qr0 = qt * 256 + wave * 32;
  const float M0 = 1.05f * 1.44269504088896f / temp[0];  // bound on folded scores
  const f32x4 minit = {-M0, -M0, -M0, -M0};
  // two Q fragment pairs: rows qr0+lo (A) and qr0+16+lo (B)
  const unsigned short* qrowA = qkv + (size_t)(b * SEQ + qr0 + lo) * 3072 + h * 64 + g * 8;
  const unsigned short* qrowB = qrowA + (size_t)16 * 3072;
  const short8 qA0 = *(const short8*)qrowA;
  const short8 qA1 = *(const short8*)(qrowA + 32);
  const short8 qB0 = *(const short8*)qrowB;
  const short8 qB1 = *(const short8*)(qrowB + 32);
  // cooperative staging: 512 threads x 16B = one 64x64 bf16 tile per array
  const int srow = tid >> 3, scol = (tid & 7) * 8;
  const unsigned short* gK = qkv + (size_t)(b * SEQ + srow) * 3072 + 1024 + h * 64 + scol;
  const unsigned short* gV = vt + ((size_t)((b * NHEADS + h) * DHEAD) + srow) * SEQ + scol;
  short8 rk = *(const short8*)gK;
  short8 rv = *(const short8*)gV;
  *(short8*)&lK[0][srow * LDT + scol] = rk;
  *(short8*)&lV[0][srow * LDT + scol] = rv;
  f32x4 oA[4] = {}, oB[4] = {};
  float lA_ = 0.f, lB_ = 0.f;
  unsigned short* PbA = &pP[wave][0];
  unsigned short* PbB = &pP[8 + wave][0];
  constexpr int NT = SEQ / 64;
  for (int t = 0; t < NT; ++t) {
    __syncthreads();  // staged writes for tile t visible; all waves done with tile t-1
    const unsigned short* Kb = &lK[t & 1][0];
    const unsigned short* Vb = &lV[t & 1][0];
    if (t + 1 < NT) {  // issue next-tile global loads; consumed at loop bottom
      rk = *(const short8*)(gK + (size_t)(t + 1) * 64 * 3072);
      rv = *(const short8*)(gV + (t + 1) * 64);
    }
    // QK^T (swapped): s*[jt][r] = S[k = jt*16+g*4+r][q = lo] - M0 (C-init)
    f32x4 sA[4], sB[4];
    __builtin_amdgcn_s_setprio(1);
#pragma unroll
    for (int jt = 0; jt < 4; ++jt) {
      short8 kf0 = *(const short8*)(Kb + (jt * 16 + lo) * LDT + g * 8);
      short8 kf1 = *(const short8*)(Kb + (jt * 16 + lo) * LDT + 32 + g * 8);
      sA[jt] = MFMA_BF16(kf1, qA1, MFMA_BF16(kf0, qA0, minit));
      sB[jt] = MFMA_BF16(kf1, qB1, MFMA_BF16(kf0, qB0, minit));
    }
    __builtin_amdgcn_s_setprio(0);
    // static-max softmax: P = exp2(s) directly; lane-partial sums, reduced once at the end
    float psA = 0.f, psB = 0.f;
#pragma unroll
    for (int jt = 0; jt < 4; ++jt) {
      float a0 = exp2f(sA[jt][0]), a1 = exp2f(sA[jt][1]);
      float a2 = exp2f(sA[jt][2]), a3 = exp2f(sA[jt][3]);
      sA[jt][0] = a0; sA[jt][1] = a1; sA[jt][2] = a2; sA[jt][3] = a3;
      psA += (a0 + a1) + (a2 + a3);
      float b0 = exp2f(sB[jt][0]), b1 = exp2f(sB[jt][1]);
      float b2 = exp2f(sB[jt][2]), b3 = exp2f(sB[jt][3]);
      sB[jt][0] = b0; sB[jt][1] = b1; sB[jt][2] = b2; sB[jt][3] = b3;
      psB += (b0 + b1) + (b2 + b3);
    }
    lA_ += psA;
    lB_ += psB;
    // P -> packed bf16 -> wave-private strips (row = q = lo), b32 writes
#pragma unroll
    for (int jt = 0; jt < 4; ++jt) {
      *(unsigned*)(PbA + lo * LDP + jt * 16 + g * 4) = cvt_pk_bf16(sA[jt][0], sA[jt][1]);
      *(unsigned*)(PbA + lo * LDP + jt * 16 + g * 4 + 2) = cvt_pk_bf16(sA[jt][2], sA[jt][3]);
      *(unsigned*)(PbB + lo * LDP + jt * 16 + g * 4) = cvt_pk_bf16(sB[jt][0], sB[jt][1]);
      *(unsigned*)(PbB + lo * LDP + jt * 16 + g * 4 + 2) = cvt_pk_bf16(sB[jt][2], sB[jt][3]);
    }
    // P fragments (B-operand): lane holds P[q=lo][k = g*8.. , +32]
    short8 pA0 = *(const short8*)(PbA + lo * LDP + g * 8);
    short8 pA1 = *(const short8*)(PbA + lo * LDP + 32 + g * 8);
    short8 pB0 = *(const short8*)(PbB + lo * LDP + g * 8);
    short8 pB1 = *(const short8*)(PbB + lo * LDP + 32 + g * 8);
    // PV (swapped): o*[c][r] = O[q=lo][d = c*16+g*4+r] ; V frags shared by both halves
    __builtin_amdgcn_s_setprio(1);
#pragma unroll
    for (int c = 0; c < 4; ++c) {
      short8 vb0 = *(const short8*)(Vb + (c * 16 + lo) * LDT + g * 8);
      short8 vb1 = *(const short8*)(Vb + (c * 16 + lo) * LDT + 32 + g * 8);
      oA[c] = MFMA_BF16(vb1, pA1, MFMA_BF16(vb0, pA0, oA[c]));
      oB[c] = MFMA_BF16(vb1, pB1, MFMA_BF16(vb0, pB0, oB[c]));
    }
    __builtin_amdgcn_s_setprio(0);
    if (t + 1 < NT) {  // write prefetched tile into the other buffer
      *(short8*)&lK[(t + 1) & 1][srow * LDT + scol] = rk;
      *(short8*)&lV[(t + 1) & 1][srow * LDT + scol] = rv;
    }
  }
  // deferred cross-g sum reduction, normalize, packed stores
  lA_ += __shfl_xor(lA_, 16);
  lA_ += __shfl_xor(lA_, 32);
  lB_ += __shfl_xor(lB_, 16);
  lB_ += __shfl_xor(lB_, 32);
  const float rA = 1.0f / lA_, rB = 1.0f / lB_;
  unsigned short* orowA = out + (size_t)(b * SEQ + qr0 + lo) * D_MODEL + h * 64 + g * 4;
  unsigned short* orowB = orowA + (size_t)16 * D_MODEL;
#pragma unroll
  for (int c = 0; c < 4; ++c)
#pragma unroll
    for (int r = 0; r < 4; r += 2) {
      *(unsigned*)(orowA + c * 16 + r) = cvt_pk_bf16(oA[c][r] * rA, oA[c][r + 1] * rA);
      *(unsigned*)(orowB + c * 16 + r) = cvt_pk_bf16(oB[c][r] * rB, oB[c][r + 1] * rB);
    }
}

// ---------------- host launch ----------------
extern "C" void kernel_launch(void* const* d_in, const int* in_sizes, int n_in, void* d_out,
                              int out_size, void* d_ws, size_t ws_size, hipStream_t stream) {
  const float* x = (const float*)d_in[0];
  const float* w_qkv = (const float*)d_in[1];
  const float* w_out = (const float*)d_in[2];
  const float* w_ffn1 = (const float*)d_in[3];
  const float* w_ffn2 = (const float*)d_in[4];
  const float* g1 = (const float*)d_in[5];
  const float* b1 = (const float*)d_in[6];
  const float* g2 = (const float*)d_in[7];
  const float* b2 = (const float*)d_in[8];
  const float* temp = (const float*)d_in[9];
  float* outp = (float*)d_out;

  char* ws = (char*)d_ws;
  size_t off = 0;
  auto alloc = [&](size_t bytes) {
    void* p = ws + off;
    off += (bytes + 255) & ~(size_t)255;
    return p;
  };
  unsigned short* wqkv_bf = (unsigned short*)alloc((size_t)3072 * 1024 * 2);
  unsigned short* wout_bf = (unsigned short*)alloc((size_t)1024 * 1024 * 2);
  unsigned short* wf1_bf = (unsigned short*)alloc((size_t)2048 * 1024 * 2);
  unsigned short* wf2_bf = (unsigned short*)alloc((size_t)1024 * 2048 * 2);
  unsigned short* h_bf = (unsigned short*)alloc((size_t)MTOK * 1024 * 2);   // reused for h2
  unsigned short* qkv_bf = (unsigned short*)alloc((size_t)MTOK * 3072 * 2); // reused for ffn1 out
  unsigned short* vt_bf = (unsigned short*)alloc((size_t)BATCH * NHEADS * DHEAD * SEQ * 2);
  unsigned short* ao_bf = (unsigned short*)alloc((size_t)MTOK * 1024 * 2);
  float* x2 = (float*)alloc((size_t)MTOK * 1024 * 4);

  // weight conversions (single launch)
  f32_to_bf16_all<<<8192, 256, 0, stream>>>(w_qkv, w_out, w_ffn1, w_ffn2, wqkv_bf, wout_bf, wf1_bf,
                                            wf2_bf);
  // LN1
  ln_fwd<<<MTOK, 256, 0, stream>>>(x, g1, b1, h_bf);
  // qkv = h @ w_qkv^T with fused per-head l2norm of q (x log2e/T) and k
  gemm_bt2<3><<<dim3(3072 / 128, MTOK / 128), 256, 0, stream>>>(h_bf, wqkv_bf, nullptr, temp,
                                                                (void*)qkv_bf, MTOK, 3072, 1024);
  // build Vt
  transpose_v<<<BATCH * NHEADS * (SEQ / 64), 256, 0, stream>>>(qkv_bf, vt_bf);
  // attention (static-max softmax, XCD-local mapping)
  attn_fwd7<<<BATCH * NHEADS * (SEQ / 256), 512, 0, stream>>>(qkv_bf, vt_bf, ao_bf, temp);
  // x2 = x + attn_out @ w_out^T
  gemm_bt2<1><<<dim3(1024 / 128, MTOK / 128), 256, 0, stream>>>(ao_bf, wout_bf, x, nullptr,
                                                                (void*)x2, MTOK, 1024, 1024);
  // LN2
  ln_fwd<<<MTOK, 256, 0, stream>>>(x2, g2, b2, h_bf);
  // ffn1 = relu(h2 @ w_ffn1^T)  (reuse qkv buffer)
  gemm_bt2<2><<<dim3(2048 / 128, MTOK / 128), 256, 0, stream>>>(h_bf, wf1_bf, nullptr, nullptr,
                                                                (void*)qkv_bf, MTOK, 2048, 1024);
  // out = x2 + ffn1 @ w_ffn2^T
  gemm_bt2<1><<<dim3(1024 / 128, MTOK / 128), 256, 0, stream>>>(qkv_bf, wf2_bf, x2, nullptr,
                                                                (void*)outp, MTOK, 1024, 2048);
}

// Round 8
// 347.220 us; speedup vs baseline: 1.1646x; 1.0592x over previous
//
#include <hip/hip_runtime.h>
#include <cstdint>
#include <cstddef>
#include <math.h>

typedef __attribute__((ext_vector_type(8))) short short8;
typedef __attribute__((ext_vector_type(4))) float f32x4;
typedef __attribute__((ext_vector_type(16))) float f32x16;
typedef __attribute__((ext_vector_type(2))) unsigned uint2v;

#define D_MODEL 1024
#define NHEADS 16
#define DHEAD 64
#define BATCH 4
#define SEQ 2048
#define MTOK (BATCH * SEQ)

__device__ __forceinline__ unsigned short f2bf(float f) {
  union { float f; unsigned u; } v; v.f = f;
  unsigned r = v.u + 0x7fffu + ((v.u >> 16) & 1u);
  return (unsigned short)(r >> 16);
}
__device__ __forceinline__ float bf2f(unsigned short u) {
  union { unsigned u; float f; } v; v.u = ((unsigned)u) << 16;
  return v.f;
}
__device__ __forceinline__ unsigned cvt_pk_bf16(float a, float b) {
  unsigned u;
  asm("v_cvt_pk_bf16_f32 %0, %1, %2" : "=v"(u) : "v"(a), "v"(b));
  return u;
}

typedef const __attribute__((address_space(1))) unsigned int* gas1_t;
typedef __attribute__((address_space(3))) unsigned int* las3_t;
// async global->LDS, 16B per lane; LDS dest must be wave-uniform base (HW adds lane*16B)
__device__ __forceinline__ void gload16(const unsigned short* g, unsigned short* l) {
  __builtin_amdgcn_global_load_lds((gas1_t)g, (las3_t)l, 16, 0, 0);
}

#define MFMA_BF16(a, b, c) __builtin_amdgcn_mfma_f32_16x16x32_bf16(a, b, c, 0, 0, 0)
#define MFMA32(a, b, c) __builtin_amdgcn_mfma_f32_32x32x16_bf16(a, b, c, 0, 0, 0)

// ---------------- fp32 -> bf16 conversion, all 4 weights in one launch ----------------
__global__ __launch_bounds__(256) void f32_to_bf16_all(const float* __restrict__ s0,
                                                       const float* __restrict__ s1,
                                                       const float* __restrict__ s2,
                                                       const float* __restrict__ s3,
                                                       unsigned short* __restrict__ d0,
                                                       unsigned short* __restrict__ d1,
                                                       unsigned short* __restrict__ d2,
                                                       unsigned short* __restrict__ d3) {
  int j = blockIdx.x * 256 + threadIdx.x;  // float4 index over concatenated ranges
  const float* s;
  unsigned short* d;
  if (j < 786432) { s = s0; d = d0; }
  else if ((j -= 786432) < 262144) { s = s1; d = d1; }
  else if ((j -= 262144) < 524288) { s = s2; d = d2; }
  else { j -= 524288; s = s3; d = d3; }
  float4 v = ((const float4*)s)[j];
  ushort4 o;
  o.x = f2bf(v.x); o.y = f2bf(v.y); o.z = f2bf(v.z); o.w = f2bf(v.w);
  ((ushort4*)d)[j] = o;
}

// ---------------- LayerNorm: fp32 in -> bf16 out ----------------
__global__ __launch_bounds__(256) void ln_fwd(const float* __restrict__ x, const float* __restrict__ g,
                                              const float* __restrict__ b,
                                              unsigned short* __restrict__ out) {
  const int row = blockIdx.x, t = threadIdx.x;
  float4 v = *(const float4*)(x + (size_t)row * D_MODEL + t * 4);
  float s = v.x + v.y + v.z + v.w;
  float s2 = v.x * v.x + v.y * v.y + v.z * v.z + v.w * v.w;
#pragma unroll
  for (int m = 1; m < 64; m <<= 1) { s += __shfl_xor(s, m); s2 += __shfl_xor(s2, m); }
  __shared__ float red[8];
  int wv = t >> 6;
  if ((t & 63) == 0) { red[wv] = s; red[4 + wv] = s2; }
  __syncthreads();
  s = red[0] + red[1] + red[2] + red[3];
  s2 = red[4] + red[5] + red[6] + red[7];
  float mu = s * (1.f / D_MODEL);
  float var = s2 * (1.f / D_MODEL) - mu * mu;
  float rs = rsqrtf(var + 1e-5f);
  float4 gg = *(const float4*)(g + t * 4);
  float4 bb = *(const float4*)(b + t * 4);
  ushort4 o;
  o.x = f2bf((v.x - mu) * rs * gg.x + bb.x);
  o.y = f2bf((v.y - mu) * rs * gg.y + bb.y);
  o.z = f2bf((v.z - mu) * rs * gg.z + bb.z);
  o.w = f2bf((v.w - mu) * rs * gg.w + bb.w);
  *(ushort4*)(out + (size_t)row * D_MODEL + t * 4) = o;
}

// ---------------- GEMM (m97 structure): C[M,N] = A[M,K] * B[N,K]^T ----------------
// XCD-chunked block swizzle. EPI: 0 bf16, 1 fp32 R+acc, 2 bf16 relu(acc),
// 3 qkv-fused: per-head l2norm of q,k rows (q also x log2e/T), v plain bf16.
template <int EPI>
__global__ __launch_bounds__(256) void gemm_bt2(const unsigned short* __restrict__ A,
                                                const unsigned short* __restrict__ B,
                                                const float* __restrict__ R,
                                                const float* __restrict__ Tptr,
                                                void* __restrict__ Cout, int M, int N, int K) {
  constexpr int BM = 128, BN = 128, BK = 32;
  __shared__ unsigned short lA[2][BM * BK], lB[2][BN * BK];
  const int tid = threadIdx.x, lane = tid & 63, wave = tid >> 6;
  const int lo = lane & 15, g = lane >> 4;
  const int nbx = gridDim.x;
  const int o = blockIdx.y * nbx + blockIdx.x;
  const int cpx = (nbx * gridDim.y) >> 3;
  const int w = (o & 7) * cpx + (o >> 3);
  const int bx = w % nbx, by = w / nbx;
  const int bm = by * BM, bn = bx * BN;
  const int wr = wave >> 1, wc = wave & 1;
  f32x4 acc[4][4] = {};
  const int c0 = wave * 128 + lane, c1 = c0 + 64;
  const unsigned short* gA0 = A + (size_t)(bm + (c0 >> 2)) * K + (c0 & 3) * 8;
  const unsigned short* gA1 = A + (size_t)(bm + (c1 >> 2)) * K + (c1 & 3) * 8;
  const unsigned short* gB0 = B + (size_t)(bn + (c0 >> 2)) * K + (c0 & 3) * 8;
  const unsigned short* gB1 = B + (size_t)(bn + (c1 >> 2)) * K + (c1 & 3) * 8;
  const int nk = K / BK;
  auto stage = [&](int buf, int kt) {
    const size_t ko = (size_t)kt * BK;
    gload16(gA0 + ko, &lA[buf][(wave * 128) * 8]);
    gload16(gA1 + ko, &lA[buf][(wave * 128 + 64) * 8]);
    gload16(gB0 + ko, &lB[buf][(wave * 128) * 8]);
    gload16(gB1 + ko, &lB[buf][(wave * 128 + 64) * 8]);
  };
  stage(0, 0);
  for (int kt = 0; kt < nk; ++kt) {
    __syncthreads();
    if (kt + 1 < nk) stage((kt + 1) & 1, kt + 1);
    const unsigned short* La = &lA[kt & 1][0];
    const unsigned short* Lb = &lB[kt & 1][0];
    short8 af[4], bfr[4];
#pragma unroll
    for (int m = 0; m < 4; ++m)
      af[m] = *(const short8*)(La + (wr * 64 + m * 16 + lo) * BK + g * 8);
#pragma unroll
    for (int n = 0; n < 4; ++n)
      bfr[n] = *(const short8*)(Lb + (wc * 64 + n * 16 + lo) * BK + g * 8);
#pragma unroll
    for (int m = 0; m < 4; ++m)
#pragma unroll
      for (int n = 0; n < 4; ++n) acc[m][n] = MFMA_BF16(af[m], bfr[n], acc[m][n]);
  }
  const int r0 = bm + wr * 64 + g * 4;
  const int c0c = bn + wc * 64 + lo;
  if (EPI == 3) {
    const int hb = bn + wc * 64;
    const bool isq = hb < 1024, isk = (hb >= 1024) && (hb < 2048);
    const float qs = 1.44269504088896f / Tptr[0];  // log2(e)/T folded into q
#pragma unroll
    for (int m = 0; m < 4; ++m)
#pragma unroll
      for (int r = 0; r < 4; ++r) {
        float sc = 1.0f;
        if (isq || isk) {
          float ss = 0.f;
#pragma unroll
          for (int n = 0; n < 4; ++n) ss += acc[m][n][r] * acc[m][n][r];
          ss += __shfl_xor(ss, 1);
          ss += __shfl_xor(ss, 2);
          ss += __shfl_xor(ss, 4);
          ss += __shfl_xor(ss, 8);
          sc = 1.0f / fmaxf(sqrtf(ss), 1e-12f);
          if (isq) sc *= qs;
        }
#pragma unroll
        for (int n = 0; n < 4; ++n) {
          size_t off = (size_t)(r0 + m * 16 + r) * N + (c0c + n * 16);
          ((unsigned short*)Cout)[off] = f2bf(acc[m][n][r] * sc);
        }
      }
  } else {
#pragma unroll
    for (int m = 0; m < 4; ++m)
#pragma unroll
      for (int n = 0; n < 4; ++n) {
#pragma unroll
        for (int r = 0; r < 4; ++r) {
          size_t off = (size_t)(r0 + m * 16 + r) * N + (c0c + n * 16);
          float v = acc[m][n][r];
          if (EPI == 0) ((unsigned short*)Cout)[off] = f2bf(v);
          else if (EPI == 1) ((float*)Cout)[off] = R[off] + v;
          else ((unsigned short*)Cout)[off] = f2bf(fmaxf(v, 0.f));
        }
      }
  }
}

// ---------------- transpose v -> Vt[b,h,d,n] ----------------
__global__ __launch_bounds__(256) void transpose_v(const unsigned short* __restrict__ qkv,
                                                   unsigned short* __restrict__ vt) {
  __shared__ unsigned short tile[64][80];
  const int blk = blockIdx.x;
  const int ntile = blk & 31, h = (blk >> 5) & 15, b = blk >> 9;
  const int t = threadIdx.x;
  const int tt = t >> 2, c4 = t & 3;
  size_t rowbase = (size_t)(b * SEQ + ntile * 64 + tt) * 3072 + h * 64 + c4 * 16;
  const unsigned short* pv = qkv + rowbase + 2048;
  *(short8*)&tile[tt][c4 * 16] = *(const short8*)pv;
  *(short8*)&tile[tt][c4 * 16 + 8] = *(const short8*)(pv + 8);
  __syncthreads();
  const int d = tt;
  short8 o0, o1;
#pragma unroll
  for (int j = 0; j < 8; ++j) o0[j] = (short)tile[c4 * 16 + j][d];
#pragma unroll
  for (int j = 0; j < 8; ++j) o1[j] = (short)tile[c4 * 16 + 8 + j][d];
  size_t vr = (size_t)((b * NHEADS + h) * DHEAD + d) * SEQ + ntile * 64 + c4 * 16;
  *(short8*)(vt + vr) = o0;
  *(short8*)(vt + vr + 8) = o1;
}

// ---------------- flash attention v8: 32x32 MFMA, fully in-register P (permlane32_swap) ----------------
// Swapped mfma(K,Q): lane holds S[k][q=lane&31] (both halves same q). Static-max via C-init=-M0.
// P -> bf16 (cvt_pk) -> permlane32_swap pairs build the PV B-fragment in registers: NO P LDS.
// K/V tiles [64][64] bf16, XOR-swizzled (slot ^= row&7), double-buffered: 32KB LDS total.
// 4 waves x 32 q-rows = 128 q/block; grid 1024 keeps the XCD-local mapping (bh = blk & 63).
__global__ __launch_bounds__(256) void attn_fwd8(const unsigned short* __restrict__ qkv,
                                                 const unsigned short* __restrict__ vt,
                                                 unsigned short* __restrict__ out,
                                                 const float* __restrict__ temp) {
  __shared__ unsigned short lK[2][64 * 64];
  __shared__ unsigned short lV[2][64 * 64];
  const int blk = blockIdx.x;
  const int bh = blk & 63, qt = blk >> 6;
  const int b = bh >> 4, h = bh & 15;
  const int tid = threadIdx.x, lane = tid & 63, wave = tid >> 6;
  const int l5 = lane >> 5, l31 = lane & 31;
  const int qr0 = qt * 128 + wave * 32;
  const float M0 = 1.05f * 1.44269504088896f / temp[0];  // bound on folded scores
  f32x16 minit;
#pragma unroll
  for (int r = 0; r < 16; ++r) minit[r] = -M0;
  // Q frags (B-operand): qf[t] elem j = Q[q = qr0+l31][d = t*16 + l5*8 + j]
  const unsigned short* qrow = qkv + (size_t)(b * SEQ + qr0 + l31) * 3072 + h * 64 + l5 * 8;
  short8 qf[4];
#pragma unroll
  for (int t = 0; t < 4; ++t) qf[t] = *(const short8*)(qrow + t * 16);
  // staging: 256 threads; thread t: rows (t>>3, t>>3+32), 16B slot t&7, swizzled dest
  const int srow = tid >> 3, slot = tid & 7;
  const int sw0 = ((slot ^ (srow & 7)) * 8);  // same swizzle for srow+32 (row&7 equal)
  const unsigned short* gK = qkv + (size_t)(b * SEQ + srow) * 3072 + 1024 + h * 64 + slot * 8;
  const unsigned short* gV = vt + ((size_t)(bh * 64) + srow) * SEQ + slot * 8;
  short8 rk0 = *(const short8*)gK;
  short8 rk1 = *(const short8*)(gK + (size_t)32 * 3072);
  short8 rv0 = *(const short8*)gV;
  short8 rv1 = *(const short8*)(gV + (size_t)32 * SEQ);
  *(short8*)&lK[0][srow * 64 + sw0] = rk0;
  *(short8*)&lK[0][(srow + 32) * 64 + sw0] = rk1;
  *(short8*)&lV[0][srow * 64 + sw0] = rv0;
  *(short8*)&lV[0][(srow + 32) * 64 + sw0] = rv1;
  f32x16 o0 = {}, o1 = {};  // O[d][q]: d-blocks 0..31 / 32..63
  float lsum = 0.f;
  constexpr int NT = SEQ / 64;
  for (int t = 0; t < NT; ++t) {
    __syncthreads();  // staged tile t visible; all waves done reading tile t-1
    const unsigned short* Kb = &lK[t & 1][0];
    const unsigned short* Vb = &lV[t & 1][0];
    if (t + 1 < NT) {  // issue next-tile global loads; written to LDS at loop bottom
      rk0 = *(const short8*)(gK + (size_t)(t + 1) * 64 * 3072);
      rk1 = *(const short8*)(gK + (size_t)((t + 1) * 64 + 32) * 3072);
      rv0 = *(const short8*)(gV + (t + 1) * 64);
      rv1 = *(const short8*)(gV + (size_t)32 * SEQ + (t + 1) * 64);
    }
#pragma unroll
    for (int tile = 0; tile < 2; ++tile) {  // two 32-key tiles
      // QK^T (swapped): S[k = tile*32 + (reg&3)+8*(reg>>2)+4*l5][q = l31] - M0
      f32x16 s = minit;
      __builtin_amdgcn_s_setprio(1);
#pragma unroll
      for (int td = 0; td < 4; ++td) {
        const int row = tile * 32 + l31;
        const int sl = ((2 * td + l5) ^ (row & 7)) * 8;
        short8 kf = *(const short8*)(Kb + row * 64 + sl);
        s = MFMA32(kf, qf[td], s);
      }
      __builtin_amdgcn_s_setprio(0);
      // static-max softmax
      float p[16];
      float ps = 0.f;
#pragma unroll
      for (int r = 0; r < 16; ++r) { p[r] = exp2f(s[r]); ps += p[r]; }
      lsum += ps;
      // pack pairs; permlane32_swap -> B-frags for PV (k = tile*32 + [0..15], [16..31])
      unsigned a0 = cvt_pk_bf16(p[0], p[1]), a1 = cvt_pk_bf16(p[2], p[3]);
      unsigned a2 = cvt_pk_bf16(p[4], p[5]), a3 = cvt_pk_bf16(p[6], p[7]);
      unsigned c0 = cvt_pk_bf16(p[8], p[9]), c1 = cvt_pk_bf16(p[10], p[11]);
      unsigned c2 = cvt_pk_bf16(p[12], p[13]), c3 = cvt_pk_bf16(p[14], p[15]);
      uint2v w0 = __builtin_amdgcn_permlane32_swap(a0, a2, false, false);
      uint2v w1 = __builtin_amdgcn_permlane32_swap(a1, a3, false, false);
      uint2v w2 = __builtin_amdgcn_permlane32_swap(c0, c2, false, false);
      uint2v w3 = __builtin_amdgcn_permlane32_swap(c1, c3, false, false);
      union { unsigned u[4]; short8 v; } f0, f1;
      f0.u[0] = w0.x; f0.u[1] = w1.x; f0.u[2] = w0.y; f0.u[3] = w1.y;
      f1.u[0] = w2.x; f1.u[1] = w3.x; f1.u[2] = w2.y; f1.u[3] = w3.y;
      // PV (swapped): O[d][q] += Vt-frag x P-frag over this tile's 32 keys
      __builtin_amdgcn_s_setprio(1);
      {
        const int vrow0 = l31, vrow1 = 32 + l31;
        const int sa = ((2 * (tile * 2) + l5) ^ (vrow0 & 7)) * 8;
        const int sb = ((2 * (tile * 2 + 1) + l5) ^ (vrow0 & 7)) * 8;  // vrow1&7 == vrow0&7
        short8 va0 = *(const short8*)(Vb + vrow0 * 64 + sa);
        short8 vb0 = *(const short8*)(Vb + vrow0 * 64 + sb);
        short8 va1 = *(const short8*)(Vb + vrow1 * 64 + sa);
        short8 vb1 = *(const short8*)(Vb + vrow1 * 64 + sb);
        o0 = MFMA32(va0, f0.v, o0);
        o0 = MFMA32(vb0, f1.v, o0);
        o1 = MFMA32(va1, f0.v, o1);
        o1 = MFMA32(vb1, f1.v, o1);
      }
      __builtin_amdgcn_s_setprio(0);
    }
    if (t + 1 < NT) {  // write prefetched tile into the other buffer
      *(short8*)&lK[(t + 1) & 1][srow * 64 + sw0] = rk0;
      *(short8*)&lK[(t + 1) & 1][(srow + 32) * 64 + sw0] = rk1;
      *(short8*)&lV[(t + 1) & 1][srow * 64 + sw0] = rv0;
      *(short8*)&lV[(t + 1) & 1][(srow + 32) * 64 + sw0] = rv1;
    }
  }
  // row sum: this lane + its q-partner in the other half; normalize + packed stores
  lsum += __shfl_xor(lsum, 32);
  const float rinv = 1.0f / lsum;
  // lane l -> q = qr0 + l31; d = dblk*32 + 4*l5 + 8*rq + rr
  unsigned short* orow = out + (size_t)(b * SEQ + qr0 + l31) * D_MODEL + h * 64 + l5 * 4;
#pragma unroll
  for (int rq = 0; rq < 4; ++rq)
#pragma unroll
    for (int rr = 0; rr < 4; rr += 2) {
      *(unsigned*)(orow + rq * 8 + rr) =
          cvt_pk_bf16(o0[rq * 4 + rr] * rinv, o0[rq * 4 + rr + 1] * rinv);
      *(unsigned*)(orow + 32 + rq * 8 + rr) =
          cvt_pk_bf16(o1[rq * 4 + rr] * rinv, o1[rq * 4 + rr + 1] * rinv);
    }
}

// ---------------- host launch ----------------
extern "C" void kernel_launch(void* const* d_in, const int* in_sizes, int n_in, void* d_out,
                              int out_size, void* d_ws, size_t ws_size, hipStream_t stream) {
  const float* x = (const float*)d_in[0];
  const float* w_qkv = (const float*)d_in[1];
  const float* w_out = (const float*)d_in[2];
  const float* w_ffn1 = (const float*)d_in[3];
  const float* w_ffn2 = (const float*)d_in[4];
  const float* g1 = (const float*)d_in[5];
  const float* b1 = (const float*)d_in[6];
  const float* g2 = (const float*)d_in[7];
  const float* b2 = (const float*)d_in[8];
  const float* temp = (const float*)d_in[9];
  float* outp = (float*)d_out;

  char* ws = (char*)d_ws;
  size_t off = 0;
  auto alloc = [&](size_t bytes) {
    void* p = ws + off;
    off += (bytes + 255) & ~(size_t)255;
    return p;
  };
  unsigned short* wqkv_bf = (unsigned short*)alloc((size_t)3072 * 1024 * 2);
  unsigned short* wout_bf = (unsigned short*)alloc((size_t)1024 * 1024 * 2);
  unsigned short* wf1_bf = (unsigned short*)alloc((size_t)2048 * 1024 * 2);
  unsigned short* wf2_bf = (unsigned short*)alloc((size_t)1024 * 2048 * 2);
  unsigned short* h_bf = (unsigned short*)alloc((size_t)MTOK * 1024 * 2);   // reused for h2
  unsigned short* qkv_bf = (unsigned short*)alloc((size_t)MTOK * 3072 * 2); // reused for ffn1 out
  unsigned short* vt_bf = (unsigned short*)alloc((size_t)BATCH * NHEADS * DHEAD * SEQ * 2);
  unsigned short* ao_bf = (unsigned short*)alloc((size_t)MTOK * 1024 * 2);
  float* x2 = (float*)alloc((size_t)MTOK * 1024 * 4);

  // weight conversions (single launch)
  f32_to_bf16_all<<<8192, 256, 0, stream>>>(w_qkv, w_out, w_ffn1, w_ffn2, wqkv_bf, wout_bf, wf1_bf,
                                            wf2_bf);
  // LN1
  ln_fwd<<<MTOK, 256, 0, stream>>>(x, g1, b1, h_bf);
  // qkv = h @ w_qkv^T with fused per-head l2norm of q (x log2e/T) and k
  gemm_bt2<3><<<dim3(3072 / 128, MTOK / 128), 256, 0, stream>>>(h_bf, wqkv_bf, nullptr, temp,
                                                                (void*)qkv_bf, MTOK, 3072, 1024);
  // build Vt
  transpose_v<<<BATCH * NHEADS * (SEQ / 64), 256, 0, stream>>>(qkv_bf, vt_bf);
  // attention (32x32 MFMA, in-register P, XCD-local mapping)
  attn_fwd8<<<BATCH * NHEADS * (SEQ / 128), 256, 0, stream>>>(qkv_bf, vt_bf, ao_bf, temp);
  // x2 = x + attn_out @ w_out^T
  gemm_bt2<1><<<dim3(1024 / 128, MTOK / 128), 256, 0, stream>>>(ao_bf, wout_bf, x, nullptr,
                                                                (void*)x2, MTOK, 1024, 1024);
  // LN2
  ln_fwd<<<MTOK, 256, 0, stream>>>(x2, g2, b2, h_bf);
  // ffn1 = relu(h2 @ w_ffn1^T)  (reuse qkv buffer)
  gemm_bt2<2><<<dim3(2048 / 128, MTOK / 128), 256, 0, stream>>>(h_bf, wf1_bf, nullptr, nullptr,
                                                                (void*)qkv_bf, MTOK, 2048, 1024);
  // out = x2 + ffn1 @ w_ffn2^T
  gemm_bt2<1><<<dim3(1024 / 128, MTOK / 128), 256, 0, stream>>>(qkv_bf, wf2_bf, x2, nullptr,
                                                                (void*)outp, MTOK, 1024, 2048);
}

// Round 9
// 325.547 us; speedup vs baseline: 1.2421x; 1.0666x over previous
//
#include <hip/hip_runtime.h>
#include <cstdint>
#include <cstddef>
#include <math.h>

typedef __attribute__((ext_vector_type(8))) short short8;
typedef __attribute__((ext_vector_type(4))) float f32x4;
typedef __attribute__((ext_vector_type(16))) float f32x16;
typedef __attribute__((ext_vector_type(2))) unsigned uint2v;

#define D_MODEL 1024
#define NHEADS 16
#define DHEAD 64
#define BATCH 4
#define SEQ 2048
#define MTOK (BATCH * SEQ)

__device__ __forceinline__ unsigned short f2bf(float f) {
  union { float f; unsigned u; } v; v.f = f;
  unsigned r = v.u + 0x7fffu + ((v.u >> 16) & 1u);
  return (unsigned short)(r >> 16);
}
__device__ __forceinline__ float bf2f(unsigned short u) {
  union { unsigned u; float f; } v; v.u = ((unsigned)u) << 16;
  return v.f;
}
__device__ __forceinline__ unsigned cvt_pk_bf16(float a, float b) {
  unsigned u;
  asm("v_cvt_pk_bf16_f32 %0, %1, %2" : "=v"(u) : "v"(a), "v"(b));
  return u;
}
// raw v_exp_f32 (2^x). Safe for x in [-126, 127]; our args are in [-62, 0].
__device__ __forceinline__ float exp2_fast(float x) {
  float r;
  asm("v_exp_f32 %0, %1" : "=v"(r) : "v"(x));
  return r;
}

typedef const __attribute__((address_space(1))) unsigned int* gas1_t;
typedef __attribute__((address_space(3))) unsigned int* las3_t;
// async global->LDS, 16B per lane; LDS dest must be wave-uniform base (HW adds lane*16B)
__device__ __forceinline__ void gload16(const unsigned short* g, unsigned short* l) {
  __builtin_amdgcn_global_load_lds((gas1_t)g, (las3_t)l, 16, 0, 0);
}

#define MFMA_BF16(a, b, c) __builtin_amdgcn_mfma_f32_16x16x32_bf16(a, b, c, 0, 0, 0)
#define MFMA32(a, b, c) __builtin_amdgcn_mfma_f32_32x32x16_bf16(a, b, c, 0, 0, 0)

// ---------------- fp32 -> bf16 conversion, all 4 weights in one launch ----------------
__global__ __launch_bounds__(256) void f32_to_bf16_all(const float* __restrict__ s0,
                                                       const float* __restrict__ s1,
                                                       const float* __restrict__ s2,
                                                       const float* __restrict__ s3,
                                                       unsigned short* __restrict__ d0,
                                                       unsigned short* __restrict__ d1,
                                                       unsigned short* __restrict__ d2,
                                                       unsigned short* __restrict__ d3) {
  int j = blockIdx.x * 256 + threadIdx.x;  // float4 index over concatenated ranges
  const float* s;
  unsigned short* d;
  if (j < 786432) { s = s0; d = d0; }
  else if ((j -= 786432) < 262144) { s = s1; d = d1; }
  else if ((j -= 262144) < 524288) { s = s2; d = d2; }
  else { j -= 524288; s = s3; d = d3; }
  float4 v = ((const float4*)s)[j];
  ushort4 o;
  o.x = f2bf(v.x); o.y = f2bf(v.y); o.z = f2bf(v.z); o.w = f2bf(v.w);
  ((ushort4*)d)[j] = o;
}

// ---------------- LayerNorm: fp32 in -> bf16 out ----------------
__global__ __launch_bounds__(256) void ln_fwd(const float* __restrict__ x, const float* __restrict__ g,
                                              const float* __restrict__ b,
                                              unsigned short* __restrict__ out) {
  const int row = blockIdx.x, t = threadIdx.x;
  float4 v = *(const float4*)(x + (size_t)row * D_MODEL + t * 4);
  float s = v.x + v.y + v.z + v.w;
  float s2 = v.x * v.x + v.y * v.y + v.z * v.z + v.w * v.w;
#pragma unroll
  for (int m = 1; m < 64; m <<= 1) { s += __shfl_xor(s, m); s2 += __shfl_xor(s2, m); }
  __shared__ float red[8];
  int wv = t >> 6;
  if ((t & 63) == 0) { red[wv] = s; red[4 + wv] = s2; }
  __syncthreads();
  s = red[0] + red[1] + red[2] + red[3];
  s2 = red[4] + red[5] + red[6] + red[7];
  float mu = s * (1.f / D_MODEL);
  float var = s2 * (1.f / D_MODEL) - mu * mu;
  float rs = rsqrtf(var + 1e-5f);
  float4 gg = *(const float4*)(g + t * 4);
  float4 bb = *(const float4*)(b + t * 4);
  ushort4 o;
  o.x = f2bf((v.x - mu) * rs * gg.x + bb.x);
  o.y = f2bf((v.y - mu) * rs * gg.y + bb.y);
  o.z = f2bf((v.z - mu) * rs * gg.z + bb.z);
  o.w = f2bf((v.w - mu) * rs * gg.w + bb.w);
  *(ushort4*)(out + (size_t)row * D_MODEL + t * 4) = o;
}

// ---------------- GEMM (m97 structure): C[M,N] = A[M,K] * B[N,K]^T ----------------
// XCD-chunked block swizzle. EPI: 0 bf16, 1 fp32 R+acc, 2 bf16 relu(acc),
// 3 qkv-fused: per-head l2norm of q,k rows (q also x log2e/T), v plain bf16.
template <int EPI>
__global__ __launch_bounds__(256) void gemm_bt2(const unsigned short* __restrict__ A,
                                                const unsigned short* __restrict__ B,
                                                const float* __restrict__ R,
                                                const float* __restrict__ Tptr,
                                                void* __restrict__ Cout, int M, int N, int K) {
  constexpr int BM = 128, BN = 128, BK = 32;
  __shared__ unsigned short lA[2][BM * BK], lB[2][BN * BK];
  const int tid = threadIdx.x, lane = tid & 63, wave = tid >> 6;
  const int lo = lane & 15, g = lane >> 4;
  const int nbx = gridDim.x;
  const int o = blockIdx.y * nbx + blockIdx.x;
  const int cpx = (nbx * gridDim.y) >> 3;
  const int w = (o & 7) * cpx + (o >> 3);
  const int bx = w % nbx, by = w / nbx;
  const int bm = by * BM, bn = bx * BN;
  const int wr = wave >> 1, wc = wave & 1;
  f32x4 acc[4][4] = {};
  const int c0 = wave * 128 + lane, c1 = c0 + 64;
  const unsigned short* gA0 = A + (size_t)(bm + (c0 >> 2)) * K + (c0 & 3) * 8;
  const unsigned short* gA1 = A + (size_t)(bm + (c1 >> 2)) * K + (c1 & 3) * 8;
  const unsigned short* gB0 = B + (size_t)(bn + (c0 >> 2)) * K + (c0 & 3) * 8;
  const unsigned short* gB1 = B + (size_t)(bn + (c1 >> 2)) * K + (c1 & 3) * 8;
  const int nk = K / BK;
  auto stage = [&](int buf, int kt) {
    const size_t ko = (size_t)kt * BK;
    gload16(gA0 + ko, &lA[buf][(wave * 128) * 8]);
    gload16(gA1 + ko, &lA[buf][(wave * 128 + 64) * 8]);
    gload16(gB0 + ko, &lB[buf][(wave * 128) * 8]);
    gload16(gB1 + ko, &lB[buf][(wave * 128 + 64) * 8]);
  };
  stage(0, 0);
  for (int kt = 0; kt < nk; ++kt) {
    __syncthreads();
    if (kt + 1 < nk) stage((kt + 1) & 1, kt + 1);
    const unsigned short* La = &lA[kt & 1][0];
    const unsigned short* Lb = &lB[kt & 1][0];
    short8 af[4], bfr[4];
#pragma unroll
    for (int m = 0; m < 4; ++m)
      af[m] = *(const short8*)(La + (wr * 64 + m * 16 + lo) * BK + g * 8);
#pragma unroll
    for (int n = 0; n < 4; ++n)
      bfr[n] = *(const short8*)(Lb + (wc * 64 + n * 16 + lo) * BK + g * 8);
#pragma unroll
    for (int m = 0; m < 4; ++m)
#pragma unroll
      for (int n = 0; n < 4; ++n) acc[m][n] = MFMA_BF16(af[m], bfr[n], acc[m][n]);
  }
  const int r0 = bm + wr * 64 + g * 4;
  const int c0c = bn + wc * 64 + lo;
  if (EPI == 3) {
    const int hb = bn + wc * 64;
    const bool isq = hb < 1024, isk = (hb >= 1024) && (hb < 2048);
    const float qs = 1.44269504088896f / Tptr[0];  // log2(e)/T folded into q
#pragma unroll
    for (int m = 0; m < 4; ++m)
#pragma unroll
      for (int r = 0; r < 4; ++r) {
        float sc = 1.0f;
        if (isq || isk) {
          float ss = 0.f;
#pragma unroll
          for (int n = 0; n < 4; ++n) ss += acc[m][n][r] * acc[m][n][r];
          ss += __shfl_xor(ss, 1);
          ss += __shfl_xor(ss, 2);
          ss += __shfl_xor(ss, 4);
          ss += __shfl_xor(ss, 8);
          sc = 1.0f / fmaxf(sqrtf(ss), 1e-12f);
          if (isq) sc *= qs;
        }
#pragma unroll
        for (int n = 0; n < 4; ++n) {
          size_t off = (size_t)(r0 + m * 16 + r) * N + (c0c + n * 16);
          ((unsigned short*)Cout)[off] = f2bf(acc[m][n][r] * sc);
        }
      }
  } else {
#pragma unroll
    for (int m = 0; m < 4; ++m)
#pragma unroll
      for (int n = 0; n < 4; ++n) {
#pragma unroll
        for (int r = 0; r < 4; ++r) {
          size_t off = (size_t)(r0 + m * 16 + r) * N + (c0c + n * 16);
          float v = acc[m][n][r];
          if (EPI == 0) ((unsigned short*)Cout)[off] = f2bf(v);
          else if (EPI == 1) ((float*)Cout)[off] = R[off] + v;
          else ((unsigned short*)Cout)[off] = f2bf(fmaxf(v, 0.f));
        }
      }
  }
}

// ---------------- transpose v -> Vt[b,h,d,n] ----------------
__global__ __launch_bounds__(256) void transpose_v(const unsigned short* __restrict__ qkv,
                                                   unsigned short* __restrict__ vt) {
  __shared__ unsigned short tile[64][80];
  const int blk = blockIdx.x;
  const int ntile = blk & 31, h = (blk >> 5) & 15, b = blk >> 9;
  const int t = threadIdx.x;
  const int tt = t >> 2, c4 = t & 3;
  size_t rowbase = (size_t)(b * SEQ + ntile * 64 + tt) * 3072 + h * 64 + c4 * 16;
  const unsigned short* pv = qkv + rowbase + 2048;
  *(short8*)&tile[tt][c4 * 16] = *(const short8*)pv;
  *(short8*)&tile[tt][c4 * 16 + 8] = *(const short8*)(pv + 8);
  __syncthreads();
  const int d = tt;
  short8 o0, o1;
#pragma unroll
  for (int j = 0; j < 8; ++j) o0[j] = (short)tile[c4 * 16 + j][d];
#pragma unroll
  for (int j = 0; j < 8; ++j) o1[j] = (short)tile[c4 * 16 + 8 + j][d];
  size_t vr = (size_t)((b * NHEADS + h) * DHEAD + d) * SEQ + ntile * 64 + c4 * 16;
  *(short8*)(vt + vr) = o0;
  *(short8*)(vt + vr + 8) = o1;
}

// ---------------- flash attention v9: 32x32 MFMA, in-register P, raw v_exp_f32 ----------------
// Swapped mfma(K,Q): lane holds S[k][q=lane&31]. Static-max via C-init=-M0 (cosine bound).
// P -> bf16 (cvt_pk) -> permlane32_swap builds PV B-frags in registers (no P LDS).
// exp2 via raw v_exp_f32 (args in [-62,0]); P-sum as a balanced tree (no ordered chain).
__global__ __launch_bounds__(256) void attn_fwd9(const unsigned short* __restrict__ qkv,
                                                 const unsigned short* __restrict__ vt,
                                                 unsigned short* __restrict__ out,
                                                 const float* __restrict__ temp) {
  __shared__ unsigned short lK[2][64 * 64];
  __shared__ unsigned short lV[2][64 * 64];
  const int blk = blockIdx.x;
  const int bh = blk & 63, qt = blk >> 6;
  const int b = bh >> 4, h = bh & 15;
  const int tid = threadIdx.x, lane = tid & 63, wave = tid >> 6;
  const int l5 = lane >> 5, l31 = lane & 31;
  const int qr0 = qt * 128 + wave * 32;
  const float M0 = 1.05f * 1.44269504088896f / temp[0];  // bound on folded scores
  f32x16 minit;
#pragma unroll
  for (int r = 0; r < 16; ++r) minit[r] = -M0;
  // Q frags (B-operand): qf[t] elem j = Q[q = qr0+l31][d = t*16 + l5*8 + j]
  const unsigned short* qrow = qkv + (size_t)(b * SEQ + qr0 + l31) * 3072 + h * 64 + l5 * 8;
  short8 qf[4];
#pragma unroll
  for (int t = 0; t < 4; ++t) qf[t] = *(const short8*)(qrow + t * 16);
  // staging: 256 threads; thread t: rows (t>>3, t>>3+32), 16B slot t&7, swizzled dest
  const int srow = tid >> 3, slot = tid & 7;
  const int sw0 = ((slot ^ (srow & 7)) * 8);  // same swizzle for srow+32 (row&7 equal)
  const unsigned short* gK = qkv + (size_t)(b * SEQ + srow) * 3072 + 1024 + h * 64 + slot * 8;
  const unsigned short* gV = vt + ((size_t)(bh * 64) + srow) * SEQ + slot * 8;
  short8 rk0 = *(const short8*)gK;
  short8 rk1 = *(const short8*)(gK + (size_t)32 * 3072);
  short8 rv0 = *(const short8*)gV;
  short8 rv1 = *(const short8*)(gV + (size_t)32 * SEQ);
  *(short8*)&lK[0][srow * 64 + sw0] = rk0;
  *(short8*)&lK[0][(srow + 32) * 64 + sw0] = rk1;
  *(short8*)&lV[0][srow * 64 + sw0] = rv0;
  *(short8*)&lV[0][(srow + 32) * 64 + sw0] = rv1;
  f32x16 o0 = {}, o1 = {};  // O[d][q]: d-blocks 0..31 / 32..63
  float lsum = 0.f;
  constexpr int NT = SEQ / 64;
  for (int t = 0; t < NT; ++t) {
    __syncthreads();  // staged tile t visible; all waves done reading tile t-1
    const unsigned short* Kb = &lK[t & 1][0];
    const unsigned short* Vb = &lV[t & 1][0];
    if (t + 1 < NT) {  // issue next-tile global loads; written to LDS at loop bottom
      rk0 = *(const short8*)(gK + (size_t)(t + 1) * 64 * 3072);
      rk1 = *(const short8*)(gK + (size_t)((t + 1) * 64 + 32) * 3072);
      rv0 = *(const short8*)(gV + (t + 1) * 64);
      rv1 = *(const short8*)(gV + (size_t)32 * SEQ + (t + 1) * 64);
    }
#pragma unroll
    for (int tile = 0; tile < 2; ++tile) {  // two 32-key tiles
      // QK^T (swapped): S[k = tile*32 + (reg&3)+8*(reg>>2)+4*l5][q = l31] - M0
      f32x16 s = minit;
      __builtin_amdgcn_s_setprio(1);
#pragma unroll
      for (int td = 0; td < 4; ++td) {
        const int row = tile * 32 + l31;
        const int sl = ((2 * td + l5) ^ (row & 7)) * 8;
        short8 kf = *(const short8*)(Kb + row * 64 + sl);
        s = MFMA32(kf, qf[td], s);
      }
      __builtin_amdgcn_s_setprio(0);
      // static-max softmax: raw v_exp_f32, balanced-tree sum
      float p[16];
#pragma unroll
      for (int r = 0; r < 16; ++r) p[r] = exp2_fast(s[r]);
      float q01 = p[0] + p[1], q23 = p[2] + p[3], q45 = p[4] + p[5], q67 = p[6] + p[7];
      float q89 = p[8] + p[9], qab = p[10] + p[11], qcd = p[12] + p[13], qef = p[14] + p[15];
      float h0 = (q01 + q23) + (q45 + q67);
      float h1 = (q89 + qab) + (qcd + qef);
      lsum += h0 + h1;
      // pack pairs; permlane32_swap -> B-frags for PV (k = tile*32 + [0..15], [16..31])
      unsigned a0 = cvt_pk_bf16(p[0], p[1]), a1 = cvt_pk_bf16(p[2], p[3]);
      unsigned a2 = cvt_pk_bf16(p[4], p[5]), a3 = cvt_pk_bf16(p[6], p[7]);
      unsigned c0 = cvt_pk_bf16(p[8], p[9]), c1 = cvt_pk_bf16(p[10], p[11]);
      unsigned c2 = cvt_pk_bf16(p[12], p[13]), c3 = cvt_pk_bf16(p[14], p[15]);
      uint2v w0 = __builtin_amdgcn_permlane32_swap(a0, a2, false, false);
      uint2v w1 = __builtin_amdgcn_permlane32_swap(a1, a3, false, false);
      uint2v w2 = __builtin_amdgcn_permlane32_swap(c0, c2, false, false);
      uint2v w3 = __builtin_amdgcn_permlane32_swap(c1, c3, false, false);
      union { unsigned u[4]; short8 v; } f0, f1;
      f0.u[0] = w0.x; f0.u[1] = w1.x; f0.u[2] = w0.y; f0.u[3] = w1.y;
      f1.u[0] = w2.x; f1.u[1] = w3.x; f1.u[2] = w2.y; f1.u[3] = w3.y;
      // PV (swapped): O[d][q] += Vt-frag x P-frag over this tile's 32 keys
      __builtin_amdgcn_s_setprio(1);
      {
        const int vrow0 = l31, vrow1 = 32 + l31;
        const int sa = ((2 * (tile * 2) + l5) ^ (vrow0 & 7)) * 8;
        const int sb = ((2 * (tile * 2 + 1) + l5) ^ (vrow0 & 7)) * 8;  // vrow1&7 == vrow0&7
        short8 va0 = *(const short8*)(Vb + vrow0 * 64 + sa);
        short8 vb0 = *(const short8*)(Vb + vrow0 * 64 + sb);
        short8 va1 = *(const short8*)(Vb + vrow1 * 64 + sa);
        short8 vb1 = *(const short8*)(Vb + vrow1 * 64 + sb);
        o0 = MFMA32(va0, f0.v, o0);
        o0 = MFMA32(vb0, f1.v, o0);
        o1 = MFMA32(va1, f0.v, o1);
        o1 = MFMA32(vb1, f1.v, o1);
      }
      __builtin_amdgcn_s_setprio(0);
    }
    if (t + 1 < NT) {  // write prefetched tile into the other buffer
      *(short8*)&lK[(t + 1) & 1][srow * 64 + sw0] = rk0;
      *(short8*)&lK[(t + 1) & 1][(srow + 32) * 64 + sw0] = rk1;
      *(short8*)&lV[(t + 1) & 1][srow * 64 + sw0] = rv0;
      *(short8*)&lV[(t + 1) & 1][(srow + 32) * 64 + sw0] = rv1;
    }
  }
  // row sum: this lane + its q-partner in the other half; normalize + packed stores
  lsum += __shfl_xor(lsum, 32);
  const float rinv = 1.0f / lsum;
  // lane l -> q = qr0 + l31; d = dblk*32 + 4*l5 + 8*rq + rr
  unsigned short* orow = out + (size_t)(b * SEQ + qr0 + l31) * D_MODEL + h * 64 + l5 * 4;
#pragma unroll
  for (int rq = 0; rq < 4; ++rq)
#pragma unroll
    for (int rr = 0; rr < 4; rr += 2) {
      *(unsigned*)(orow + rq * 8 + rr) =
          cvt_pk_bf16(o0[rq * 4 + rr] * rinv, o0[rq * 4 + rr + 1] * rinv);
      *(unsigned*)(orow + 32 + rq * 8 + rr) =
          cvt_pk_bf16(o1[rq * 4 + rr] * rinv, o1[rq * 4 + rr + 1] * rinv);
    }
}

// ---------------- host launch ----------------
extern "C" void kernel_launch(void* const* d_in, const int* in_sizes, int n_in, void* d_out,
                              int out_size, void* d_ws, size_t ws_size, hipStream_t stream) {
  const float* x = (const float*)d_in[0];
  const float* w_qkv = (const float*)d_in[1];
  const float* w_out = (const float*)d_in[2];
  const float* w_ffn1 = (const float*)d_in[3];
  const float* w_ffn2 = (const float*)d_in[4];
  const float* g1 = (const float*)d_in[5];
  const float* b1 = (const float*)d_in[6];
  const float* g2 = (const float*)d_in[7];
  const float* b2 = (const float*)d_in[8];
  const float* temp = (const float*)d_in[9];
  float* outp = (float*)d_out;

  char* ws = (char*)d_ws;
  size_t off = 0;
  auto alloc = [&](size_t bytes) {
    void* p = ws + off;
    off += (bytes + 255) & ~(size_t)255;
    return p;
  };
  unsigned short* wqkv_bf = (unsigned short*)alloc((size_t)3072 * 1024 * 2);
  unsigned short* wout_bf = (unsigned short*)alloc((size_t)1024 * 1024 * 2);
  unsigned short* wf1_bf = (unsigned short*)alloc((size_t)2048 * 1024 * 2);
  unsigned short* wf2_bf = (unsigned short*)alloc((size_t)1024 * 2048 * 2);
  unsigned short* h_bf = (unsigned short*)alloc((size_t)MTOK * 1024 * 2);   // reused for h2
  unsigned short* qkv_bf = (unsigned short*)alloc((size_t)MTOK * 3072 * 2); // reused for ffn1 out
  unsigned short* vt_bf = (unsigned short*)alloc((size_t)BATCH * NHEADS * DHEAD * SEQ * 2);
  unsigned short* ao_bf = (unsigned short*)alloc((size_t)MTOK * 1024 * 2);
  float* x2 = (float*)alloc((size_t)MTOK * 1024 * 4);

  // weight conversions (single launch)
  f32_to_bf16_all<<<8192, 256, 0, stream>>>(w_qkv, w_out, w_ffn1, w_ffn2, wqkv_bf, wout_bf, wf1_bf,
                                            wf2_bf);
  // LN1
  ln_fwd<<<MTOK, 256, 0, stream>>>(x, g1, b1, h_bf);
  // qkv = h @ w_qkv^T with fused per-head l2norm of q (x log2e/T) and k
  gemm_bt2<3><<<dim3(3072 / 128, MTOK / 128), 256, 0, stream>>>(h_bf, wqkv_bf, nullptr, temp,
                                                                (void*)qkv_bf, MTOK, 3072, 1024);
  // build Vt
  transpose_v<<<BATCH * NHEADS * (SEQ / 64), 256, 0, stream>>>(qkv_bf, vt_bf);
  // attention (32x32 MFMA, in-register P, raw v_exp, XCD-local mapping)
  attn_fwd9<<<BATCH * NHEADS * (SEQ / 128), 256, 0, stream>>>(qkv_bf, vt_bf, ao_bf, temp);
  // x2 = x + attn_out @ w_out^T
  gemm_bt2<1><<<dim3(1024 / 128, MTOK / 128), 256, 0, stream>>>(ao_bf, wout_bf, x, nullptr,
                                                                (void*)x2, MTOK, 1024, 1024);
  // LN2
  ln_fwd<<<MTOK, 256, 0, stream>>>(x2, g2, b2, h_bf);
  // ffn1 = relu(h2 @ w_ffn1^T)  (reuse qkv buffer)
  gemm_bt2<2><<<dim3(2048 / 128, MTOK / 128), 256, 0, stream>>>(h_bf, wf1_bf, nullptr, nullptr,
                                                                (void*)qkv_bf, MTOK, 2048, 1024);
  // out = x2 + ffn1 @ w_ffn2^T
  gemm_bt2<1><<<dim3(1024 / 128, MTOK / 128), 256, 0, stream>>>(qkv_bf, wf2_bf, x2, nullptr,
                                                                (void*)outp, MTOK, 1024, 2048);
}